// Round 6
// baseline (265.020 us; speedup 1.0000x reference)
//
#include <hip/hip_runtime.h>
#include <cstdint>
#include <cstddef>

typedef __bf16 bf16_t;
typedef __bf16 bf16x8 __attribute__((ext_vector_type(8)));
typedef __bf16 bf16x4v __attribute__((ext_vector_type(4)));
typedef float f32x16 __attribute__((ext_vector_type(16)));

static __device__ __forceinline__ f32x16 mfma32(bf16x8 a, bf16x8 b, f32x16 c) {
  return __builtin_amdgcn_mfma_f32_32x32x16_bf16(a, b, c, 0, 0, 0);
}

// Direct global->LDS DMA, 16B per lane (attn kernel only).
static __device__ __forceinline__ void gld_lds16(const void* g, void* l) {
  __builtin_amdgcn_global_load_lds(
      (const __attribute__((address_space(1))) unsigned int*)g,
      (__attribute__((address_space(3))) unsigned int*)l, 16, 0, 0);
}

#define CEXP_CONST 0.12754582f  // (1/sqrt(128)) * log2(e)

// ---------------------------------------------------------------------------
// Workspace layout (bytes):
//   [0, 768K)        Wt    bf16 [3][128][1024]
//   [1M, 9M)         Qp    bf16 [8][4096][128]
//   [9M, 17M)        Kp    bf16 [8][4096][128]
//   [17M, 25M)       Vt    bf16 [8][128][4096]
//   [32M, 64M)       Opart f32  [2*256][128][128]
//   [64M, +256K)     Mpart f32  [2*256*128]
//   [64M+256K,+256K) Lpart f32  [2*256*128]
// ---------------------------------------------------------------------------

__global__ void wt_kernel(const float* __restrict__ Wq, const float* __restrict__ Wk,
                          const float* __restrict__ Wv, bf16_t* __restrict__ Wt) {
  int t = blockIdx.x * 256 + threadIdx.x;
  int tensor = t >> 17;
  int r = t & 131071;
  int kk = r >> 7, n = r & 127;
  const float* W = tensor == 0 ? Wq : (tensor == 1 ? Wk : Wv);
  Wt[(size_t)tensor * 131072 + (size_t)n * 1024 + kk] = (bf16_t)W[(size_t)kk * 128 + n];
}

// X[32768,1024]f32 @ W[1024,128] -> bf16.
// A: per-lane direct global loads, register double-buffered one iter ahead
//    (no barrier ever blocks the A stream; vmcnt never drained in-loop).
// W: reg-staged into padded LDS rows (136B), issue-early / write-late (T14),
//    single buffer guarded by two raw s_barriers per iteration.
// BK=64, 16 iterations. ty: 0=Q, 1=K (row-major out), 2=V (transposed out).
__global__ __launch_bounds__(256, 3) void proj_kernel(
    const float* __restrict__ xq, const float* __restrict__ xk, const float* __restrict__ xv,
    const bf16_t* __restrict__ WtAll,
    bf16_t* __restrict__ Qp, bf16_t* __restrict__ Kp, bf16_t* __restrict__ Vt) {
  // W tile [128 n][64 k] bf16, row stride 136B -> 17408B; epilogue reuses [0,33792).
  __shared__ __align__(16) char smc[33792];
  const int tid = threadIdx.x;
  const int ty = blockIdx.y;
  const int bm = blockIdx.x;
  const float* X = (ty == 0) ? xq : (ty == 1) ? xk : xv;
  const bf16_t* W = WtAll + (size_t)ty * 131072;
  const int lane = tid & 63;
  const int w = tid >> 6;
  const int l31 = lane & 31, h = lane >> 5;

  f32x16 acc[4];
#pragma unroll
  for (int nf = 0; nf < 4; ++nf)
#pragma unroll
    for (int r = 0; r < 16; ++r) acc[nf][r] = 0.0f;

  // W staging: wave w owns n-rows [w*32, w*32+32). 4 chunks of 8 rows x 8 slots.
  int wgo[4], wlo[4];
#pragma unroll
  for (int i = 0; i < 4; ++i) {
    int n = w * 32 + i * 8 + (lane >> 3);
    wgo[i] = n * 2048 + (lane & 7) * 16;   // global: Wt row n (2KB), k-slot
    wlo[i] = n * 136 + (lane & 7) * 16;    // LDS: padded row
  }
  const char* wg = (const char*)W;
  const float* ap = X + (size_t)(bm * 128 + w * 32 + l31) * 1024 + h * 8;

  uint4 wreg[4];
  float4 aA[8], aB[8];

  // ---- prologue: W(0) to LDS, A(0) to regs ----
#pragma unroll
  for (int i = 0; i < 4; ++i) wreg[i] = *(const uint4*)(wg + wgo[i]);
#pragma unroll
  for (int j = 0; j < 8; ++j) aA[j] = *(const float4*)(ap + (j >> 1) * 16 + (j & 1) * 4);
#pragma unroll
  for (int i = 0; i < 4; ++i) *(uint4*)(&smc[wlo[i]]) = wreg[i];
  __syncthreads();

  auto body = [&](int kt, float4 (&cur)[8], float4 (&nxt)[8]) {
    const bool more = (kt + 1 < 16);
    if (more) {
      // issue W(kt+1) then A(kt+1): in-order vmcnt retire means the later
      // ds_write's auto-wait covers exactly the 4 W loads (A stays in flight).
#pragma unroll
      for (int i = 0; i < 4; ++i)
        wreg[i] = *(const uint4*)(wg + (kt + 1) * 128 + wgo[i]);
#pragma unroll
      for (int j = 0; j < 8; ++j)
        nxt[j] = *(const float4*)(ap + (kt + 1) * 64 + (j >> 1) * 16 + (j & 1) * 4);
    }
    __builtin_amdgcn_s_setprio(1);
#pragma unroll
    for (int ks = 0; ks < 4; ++ks) {
      float4 u0 = cur[2 * ks], u1 = cur[2 * ks + 1];
      bf16x8 af;
      af[0] = (bf16_t)u0.x; af[1] = (bf16_t)u0.y; af[2] = (bf16_t)u0.z; af[3] = (bf16_t)u0.w;
      af[4] = (bf16_t)u1.x; af[5] = (bf16_t)u1.y; af[6] = (bf16_t)u1.z; af[7] = (bf16_t)u1.w;
      const int so = (2 * ks + h) * 16;
#pragma unroll
      for (int nf = 0; nf < 4; ++nf) {
        int n = nf * 32 + l31;
        bf16x8 wf = *(const bf16x8*)(&smc[n * 136 + so]);
        acc[nf] = mfma32(af, wf, acc[nf]);
      }
    }
    __builtin_amdgcn_s_setprio(0);
    asm volatile("s_barrier" ::: "memory");  // all waves done reading W[kt]
    if (more) {
#pragma unroll
      for (int i = 0; i < 4; ++i) *(uint4*)(&smc[wlo[i]]) = wreg[i];
      asm volatile("s_waitcnt lgkmcnt(0)" ::: "memory");
    }
    asm volatile("s_barrier" ::: "memory");  // W[kt+1] visible to all waves
  };

  for (int kt2 = 0; kt2 < 8; ++kt2) {
    body(2 * kt2, aA, aB);
    body(2 * kt2 + 1, aB, aA);
  }

  // ---- epilogue (unchanged; WRITE_SIZE-validated in R4) ----
  if (ty < 2) {
    constexpr int RS = 264;
#pragma unroll
    for (int nf = 0; nf < 4; ++nf)
#pragma unroll
      for (int r = 0; r < 16; ++r) {
        int rowL = w * 32 + (r & 3) + 8 * (r >> 2) + 4 * h;
        *(bf16_t*)(smc + rowL * RS + (nf * 32 + l31) * 2) = (bf16_t)acc[nf][r];
      }
    __syncthreads();
    bf16_t* O = (ty == 0) ? Qp : Kp;
    char* obase = (char*)(O + (size_t)(bm * 128) * 128);
#pragma unroll
    for (int ii = 0; ii < 8; ++ii) {
      int g = ii * 256 + tid;
      int rr = g >> 4, ch = g & 15;
      uint4 vv = *(const uint4*)(smc + rr * RS + ch * 16);
      *(uint4*)(obase + rr * 256 + ch * 16) = vv;
    }
  } else {
#pragma unroll
    for (int nf = 0; nf < 4; ++nf)
#pragma unroll
      for (int rg = 0; rg < 4; ++rg) {
        int n = nf * 32 + l31;
        bf16x4v bv;
#pragma unroll
        for (int j = 0; j < 4; ++j) bv[j] = (bf16_t)acc[nf][rg * 4 + j];
        int byt = n * 256 + (((4 * w + rg) ^ (n & 7)) << 4) + 8 * h;
        *(uint2*)(smc + byt) = __builtin_bit_cast(uint2, bv);
      }
    __syncthreads();
    const int bb = bm >> 5;
    const int r0v = (bm & 31) * 128;
#pragma unroll
    for (int i = 0; i < 8; ++i) {
      int c = tid + 256 * i;
      int n = c >> 4, sl = c & 15;
      uint4 vv = *(const uint4*)(smc + n * 256 + ((sl ^ (n & 7)) << 4));
      *(uint4*)(Vt + (size_t)(bb * 128 + n) * 4096 + r0v + sl * 8) = vv;
    }
  }
}

// Build PV A-fragment in-register: 4x v_cvt_pk_bf16_f32 + 4x shfl_xor(32).
template <int B0>
static __device__ __forceinline__ bf16x8 build_pf(const f32x16& s, int h) {
  unsigned c0, c1, c2, c3;
  asm("v_cvt_pk_bf16_f32 %0, %1, %2" : "=v"(c0) : "v"(s[B0 + 0]), "v"(s[B0 + 1]));
  asm("v_cvt_pk_bf16_f32 %0, %1, %2" : "=v"(c1) : "v"(s[B0 + 2]), "v"(s[B0 + 3]));
  asm("v_cvt_pk_bf16_f32 %0, %1, %2" : "=v"(c2) : "v"(s[B0 + 4]), "v"(s[B0 + 5]));
  asm("v_cvt_pk_bf16_f32 %0, %1, %2" : "=v"(c3) : "v"(s[B0 + 6]), "v"(s[B0 + 7]));
  unsigned x0 = (unsigned)__shfl_xor((int)c0, 32);
  unsigned x1 = (unsigned)__shfl_xor((int)c1, 32);
  unsigned x2 = (unsigned)__shfl_xor((int)c2, 32);
  unsigned x3 = (unsigned)__shfl_xor((int)c3, 32);
  uint4 u;
  u.x = h ? x2 : c0;
  u.y = h ? x3 : c1;
  u.z = h ? c2 : x0;
  u.w = h ? c3 : x1;
  return __builtin_bit_cast(bf16x8, u);
}

// Flash attention (unchanged from R5: gld_lds dbuf, counted vmcnt(8)).
template <int SPLIT>
__global__ __launch_bounds__(256, 2) void attn_kernel(
    const bf16_t* __restrict__ Qp, const bf16_t* __restrict__ Kp,
    const bf16_t* __restrict__ Vt, float* __restrict__ out,
    float* __restrict__ Opart, float* __restrict__ Mpart, float* __restrict__ Lpart) {
  __shared__ __align__(16) char smc[65536];  // 2 x (K 16K | V 16K)
  const int tid = threadIdx.x;
  const int lane = tid & 63, w = tid >> 6;
  const int l31 = lane & 31, h = lane >> 5;
  const int bid = blockIdx.x;
  const int b = bid & 7;
  const int qt = (bid >> 3) & 31;
  const int s = bid >> 8;
  const int NT = 64 / SPLIT;
  const float CEXP = CEXP_CONST;
  const int qbase = qt * 128 + w * 32;
  const int sw0 = (l31 ^ (l31 >> 3)) & 7;
  const int sw1 = sw0 ^ 4;

  bf16x8 qf[8];
  const bf16_t* qrow = Qp + (size_t)(b * 4096 + qbase + l31) * 128 + h * 8;
#pragma unroll
  for (int db = 0; db < 8; ++db) qf[db] = *(const bf16x8*)(qrow + db * 16);

  int swv[4];
#pragma unroll
  for (int nf = 0; nf < 4; ++nf) swv[nf] = (l31 & 7) ^ ((4 * nf + (l31 >> 3)) & 7);

  const int rl = lane >> 4, slK = lane & 15;
  const int dl = lane >> 3, slV = lane & 7;
  int koff[4], voff[4];
#pragma unroll
  for (int i = 0; i < 4; ++i) {
    int r = w * 16 + i * 4 + rl;
    int swr = (r ^ (r >> 3)) & 7;
    koff[i] = r * 256 + (((slK & 8) | ((slK & 7) ^ swr)) << 4);
    int d = w * 32 + i * 8 + dl;
    int swd = (d ^ (d >> 3)) & 7;
    voff[i] = d * 8192 + ((slV ^ swd) << 4);
  }
  const char* kpb = (const char*)Kp + (size_t)b * 1048576 + (size_t)s * NT * 16384;
  const char* vpb = (const char*)Vt + (size_t)b * 1048576 + (size_t)s * NT * 128;

  f32x16 oacc[4];
#pragma unroll
  for (int nf = 0; nf < 4; ++nf)
#pragma unroll
    for (int r = 0; r < 16; ++r) oacc[nf][r] = 0.0f;
  float m_run = -3.0e38f, lacc = 0.0f;

  auto stage = [&](int tt, int bufb) {
    const char* kb = kpb + (size_t)tt * 16384;
    const char* vb = vpb + (size_t)tt * 128;
    char* lk = smc + bufb + w * 4096;
    char* lv = smc + bufb + 16384 + w * 4096;
#pragma unroll
    for (int i = 0; i < 4; ++i) {
      gld_lds16(kb + koff[i], lk + i * 1024);
      gld_lds16(vb + voff[i], lv + i * 1024);
    }
  };

  stage(0, 0);
  stage(1, 32768);

  for (int t = 0; t < NT; ++t) {
    asm volatile("s_waitcnt vmcnt(8)" ::: "memory");
    __builtin_amdgcn_s_barrier();
    const char* kb = smc + (t & 1) * 32768;
    const char* vb = kb + 16384;

    f32x16 s0, s1;
#pragma unroll
    for (int i = 0; i < 16; ++i) { s0[i] = 0.0f; s1[i] = 0.0f; }
    __builtin_amdgcn_s_setprio(1);
#pragma unroll
    for (int db = 0; db < 8; ++db) {
      const int q = 2 * db + h;
      bf16x8 k0 = *(const bf16x8*)(kb + l31 * 256 + (((q & 8) | ((q & 7) ^ sw0)) << 4));
      bf16x8 k1 = *(const bf16x8*)(kb + (32 + l31) * 256 + (((q & 8) | ((q & 7) ^ sw1)) << 4));
      s0 = mfma32(k0, qf[db], s0);
      s1 = mfma32(k1, qf[db], s1);
    }
    __builtin_amdgcn_s_setprio(0);

    float tmax = fmaxf(s0[0], s1[0]);
#pragma unroll
    for (int i = 1; i < 16; ++i) tmax = fmaxf(tmax, fmaxf(s0[i], s1[i]));
    tmax = fmaxf(tmax, __shfl_xor(tmax, 32));
    if (__any(tmax > m_run + 62.0f)) {
      float mnew = fmaxf(m_run, tmax);
      float fac = exp2f((m_run - mnew) * CEXP);
      m_run = mnew;
      lacc *= fac;
#pragma unroll
      for (int r = 0; r < 16; ++r) {
        float fr = __shfl(fac, (r & 3) + 8 * (r >> 2) + 4 * h);
#pragma unroll
        for (int nf = 0; nf < 4; ++nf) oacc[nf][r] *= fr;
      }
    }
    const float mc = m_run * CEXP;
#pragma unroll
    for (int i = 0; i < 16; ++i) s0[i] = exp2f(fmaf(s0[i], CEXP, -mc));
#pragma unroll
    for (int i = 0; i < 16; ++i) s1[i] = exp2f(fmaf(s1[i], CEXP, -mc));
    float a0 = 0.f, a1 = 0.f, a2 = 0.f, a3 = 0.f;
#pragma unroll
    for (int i = 0; i < 16; i += 4) {
      a0 += s0[i] + s1[i];         a1 += s0[i + 1] + s1[i + 1];
      a2 += s0[i + 2] + s1[i + 2]; a3 += s0[i + 3] + s1[i + 3];
    }
    lacc += (a0 + a1) + (a2 + a3);

    __builtin_amdgcn_s_setprio(1);
    {
      bf16x8 pf = build_pf<0>(s0, h);
#pragma unroll
      for (int nf = 0; nf < 4; ++nf) {
        bf16x8 vf = *(const bf16x8*)(vb + (nf * 32 + l31) * 128 + (((0 + h) ^ swv[nf]) << 4));
        oacc[nf] = mfma32(pf, vf, oacc[nf]);
      }
    }
    {
      bf16x8 pf = build_pf<8>(s0, h);
#pragma unroll
      for (int nf = 0; nf < 4; ++nf) {
        bf16x8 vf = *(const bf16x8*)(vb + (nf * 32 + l31) * 128 + (((2 + h) ^ swv[nf]) << 4));
        oacc[nf] = mfma32(pf, vf, oacc[nf]);
      }
    }
    {
      bf16x8 pf = build_pf<0>(s1, h);
#pragma unroll
      for (int nf = 0; nf < 4; ++nf) {
        bf16x8 vf = *(const bf16x8*)(vb + (nf * 32 + l31) * 128 + (((4 + h) ^ swv[nf]) << 4));
        oacc[nf] = mfma32(pf, vf, oacc[nf]);
      }
    }
    {
      bf16x8 pf = build_pf<8>(s1, h);
#pragma unroll
      for (int nf = 0; nf < 4; ++nf) {
        bf16x8 vf = *(const bf16x8*)(vb + (nf * 32 + l31) * 128 + (((6 + h) ^ swv[nf]) << 4));
        oacc[nf] = mfma32(pf, vf, oacc[nf]);
      }
    }
    __builtin_amdgcn_s_setprio(0);

    __builtin_amdgcn_s_barrier();
    stage((t + 2) & (NT - 1), (t & 1) * 32768);
  }
  asm volatile("s_waitcnt vmcnt(0)" ::: "memory");

  lacc += __shfl_xor(lacc, 32);
  if (SPLIT == 1) {
    const float inv = 1.0f / lacc;
    float* ob = out + (size_t)(b * 4096 + qbase) * 128;
#pragma unroll
    for (int r = 0; r < 16; ++r) {
      const int rowD = (r & 3) + 8 * (r >> 2) + 4 * h;
      float ir = __shfl(inv, rowD);
#pragma unroll
      for (int nf = 0; nf < 4; ++nf)
        ob[(size_t)rowD * 128 + nf * 32 + l31] = oacc[nf][r] * ir;
    }
  } else {
    const int pb = s * 256 + b * 32 + qt;
    if (lane < 32) {
      Mpart[pb * 128 + w * 32 + l31] = m_run;
      Lpart[pb * 128 + w * 32 + l31] = lacc;
    }
    float* ob = Opart + ((size_t)pb * 128 + w * 32) * 128;
#pragma unroll
    for (int r = 0; r < 16; ++r) {
      const int rowD = (r & 3) + 8 * (r >> 2) + 4 * h;
#pragma unroll
      for (int nf = 0; nf < 4; ++nf)
        ob[(size_t)rowD * 128 + nf * 32 + l31] = oacc[nf][r];
    }
  }
}

// Combine 2 split partials. grid 4096 x 256: 8 rows/block, 32 lanes/row (float4).
__global__ __launch_bounds__(256) void combine_kernel(
    const float* __restrict__ Opart, const float* __restrict__ Mpart,
    const float* __restrict__ Lpart, float* __restrict__ out) {
  const int g = blockIdx.x * 8 + (threadIdx.x >> 5);
  const int lane32 = threadIdx.x & 31;
  const int b = g >> 12;
  const int pos = g & 4095;
  const int qt = pos >> 7;
  const int row = pos & 127;
  const int i0 = (b * 32 + qt) * 128 + row;
  const int i1 = (256 + b * 32 + qt) * 128 + row;
  const float m0 = Mpart[i0], m1 = Mpart[i1];
  const float l0 = Lpart[i0], l1 = Lpart[i1];
  const float m = fmaxf(m0, m1);
  const float w0 = exp2f((m0 - m) * CEXP_CONST);
  const float w1 = exp2f((m1 - m) * CEXP_CONST);
  const float inv = 1.0f / (w0 * l0 + w1 * l1);
  const float4 o0 = *(const float4*)(Opart + (size_t)i0 * 128 + lane32 * 4);
  const float4 o1 = *(const float4*)(Opart + (size_t)i1 * 128 + lane32 * 4);
  float4 o;
  o.x = (w0 * o0.x + w1 * o1.x) * inv;
  o.y = (w0 * o0.y + w1 * o1.y) * inv;
  o.z = (w0 * o0.z + w1 * o1.z) * inv;
  o.w = (w0 * o0.w + w1 * o1.w) * inv;
  *(float4*)(out + (size_t)g * 128 + lane32 * 4) = o;
}

extern "C" void kernel_launch(void* const* d_in, const int* in_sizes, int n_in,
                              void* d_out, int out_size, void* d_ws, size_t ws_size,
                              hipStream_t stream) {
  const float* q  = (const float*)d_in[0];
  const float* k  = (const float*)d_in[1];
  const float* v  = (const float*)d_in[2];
  const float* Wq = (const float*)d_in[3];
  const float* Wk = (const float*)d_in[4];
  const float* Wv = (const float*)d_in[5];
  float* out = (float*)d_out;
  char* ws = (char*)d_ws;
  bf16_t* Wt = (bf16_t*)(ws);
  bf16_t* Qp = (bf16_t*)(ws + (size_t)(1u << 20));
  bf16_t* Kp = (bf16_t*)(ws + (size_t)(9u << 20));
  bf16_t* Vt = (bf16_t*)(ws + (size_t)(17u << 20));
  float* Opart = (float*)(ws + (size_t)(32u << 20));
  float* Mpart = (float*)(ws + (size_t)(64u << 20));
  float* Lpart = (float*)(ws + (size_t)(64u << 20) + (256u << 10));

  hipLaunchKernelGGL(wt_kernel, dim3(1536), dim3(256), 0, stream, Wq, Wk, Wv, Wt);
  hipLaunchKernelGGL(proj_kernel, dim3(256, 3), dim3(256), 0, stream, q, k, v, Wt, Qp, Kp, Vt);

  if (ws_size >= ((size_t)65 << 20)) {
    hipLaunchKernelGGL((attn_kernel<2>), dim3(512), dim3(256), 0, stream,
                       Qp, Kp, Vt, out, Opart, Mpart, Lpart);
    hipLaunchKernelGGL(combine_kernel, dim3(4096), dim3(256), 0, stream,
                       Opart, Mpart, Lpart, out);
  } else {
    hipLaunchKernelGGL((attn_kernel<1>), dim3(256), dim3(256), 0, stream,
                       Qp, Kp, Vt, out, Opart, Mpart, Lpart);
  }
}

// Round 7
// 237.678 us; speedup vs baseline: 1.1150x; 1.1150x over previous
//
#include <hip/hip_runtime.h>
#include <cstdint>
#include <cstddef>

typedef __bf16 bf16_t;
typedef __bf16 bf16x8 __attribute__((ext_vector_type(8)));
typedef __bf16 bf16x4v __attribute__((ext_vector_type(4)));
typedef float f32x16 __attribute__((ext_vector_type(16)));

static __device__ __forceinline__ f32x16 mfma32(bf16x8 a, bf16x8 b, f32x16 c) {
  return __builtin_amdgcn_mfma_f32_32x32x16_bf16(a, b, c, 0, 0, 0);
}

// Direct global->LDS DMA, 16B per lane (attn kernel only).
static __device__ __forceinline__ void gld_lds16(const void* g, void* l) {
  __builtin_amdgcn_global_load_lds(
      (const __attribute__((address_space(1))) unsigned int*)g,
      (__attribute__((address_space(3))) unsigned int*)l, 16, 0, 0);
}

#define CEXP_CONST 0.12754582f  // (1/sqrt(128)) * log2(e)

// ---------------------------------------------------------------------------
// Workspace layout (bytes):
//   [0, 768K)        Wt    bf16 [3][128][1024]
//   [1M, 9M)         Qp    bf16 [8][4096][128]
//   [9M, 17M)        Kp    bf16 [8][4096][128]
//   [17M, 25M)       Vt    bf16 [8][128][4096]
//   [32M, 64M)       Opart f32  [2*256][128][128]
//   [64M, +256K)     Mpart f32  [2*256*128]
//   [64M+256K,+256K) Lpart f32  [2*256*128]
// ---------------------------------------------------------------------------

__global__ void wt_kernel(const float* __restrict__ Wq, const float* __restrict__ Wk,
                          const float* __restrict__ Wv, bf16_t* __restrict__ Wt) {
  int t = blockIdx.x * 256 + threadIdx.x;
  int tensor = t >> 17;
  int r = t & 131071;
  int kk = r >> 7, n = r & 127;
  const float* W = tensor == 0 ? Wq : (tensor == 1 ? Wk : Wv);
  Wt[(size_t)tensor * 131072 + (size_t)n * 1024 + kk] = (bf16_t)W[(size_t)kk * 128 + n];
}

// X[32768,1024]f32 @ W[1024,128] -> bf16.
// 512 threads (8 waves: 4 m-blocks x 2 n-halves). BK=128, 8 outer steps.
// A staged via 512B-contiguous row-chunk loads (DRAM-page-friendly), converted
// to bf16 in-register, ds_written to swizzled LDS. W same. Single LDS buffer,
// T14 issue-early: next tile's global loads issue before compute.
// ty: 0=Q, 1=K (row-major out), 2=V (transposed out).
__global__ __launch_bounds__(512, 2) void proj_kernel(
    const float* __restrict__ xq, const float* __restrict__ xk, const float* __restrict__ xv,
    const bf16_t* __restrict__ WtAll,
    bf16_t* __restrict__ Qp, bf16_t* __restrict__ Kp, bf16_t* __restrict__ Vt) {
  // A: [0,32K) [128 m][256B k-swz]; W: [32K,64K) [128 n][256B k-swz].
  __shared__ __align__(16) char smc[65536];
  const int tid = threadIdx.x;
  const int ty = blockIdx.y;
  const int bm = blockIdx.x;
  const float* X = (ty == 0) ? xq : (ty == 1) ? xk : xv;
  const bf16_t* Wg = WtAll + (size_t)ty * 131072;
  const int lane = tid & 63;
  const int w = tid >> 6;          // wave 0..7
  const int l31 = lane & 31, h = lane >> 5;
  const int wm = w & 3, nh = w >> 2;

  f32x16 acc[2];
#pragma unroll
  for (int nf = 0; nf < 2; ++nf)
#pragma unroll
    for (int r = 0; r < 16; ++r) acc[nf][r] = 0.0f;

  // A staging: j<8: row = j*16 + (tid>>5), colb = (tid&31)*16  (512B row-chunks)
  const int arow = tid >> 5;                 // 0..15
  const int acolb = (tid & 31) * 16;
  const char* aG = (const char*)X + (size_t)(bm * 128) * 4096 + acolb;
  const int aslot = (tid & 31) >> 1, aoff8 = (tid & 1) * 8;
  // W staging: j<4: n = j*32 + (tid>>4), c = (tid&15)*16 (256B row-chunks)
  const int wn = tid >> 4;                   // 0..31
  const int wc = (tid & 15) * 16;
  const char* wG = (const char*)Wg + (size_t)wn * 2048 + wc;

  float4 aS[8];
  uint4 wS[4];

  auto issue = [&](int kt) {
#pragma unroll
    for (int j = 0; j < 8; ++j)
      aS[j] = *(const float4*)(aG + (size_t)(j * 16 + arow) * 4096 + kt * 512);
#pragma unroll
    for (int j = 0; j < 4; ++j)
      wS[j] = *(const uint4*)(wG + (size_t)j * 65536 + kt * 256);
  };
  auto writeLds = [&]() {
#pragma unroll
    for (int j = 0; j < 8; ++j) {
      int row = j * 16 + arow;
      bf16x4v bv;
      bv[0] = (bf16_t)aS[j].x; bv[1] = (bf16_t)aS[j].y;
      bv[2] = (bf16_t)aS[j].z; bv[3] = (bf16_t)aS[j].w;
      *(uint2*)(smc + row * 256 + ((aslot ^ (row & 7)) << 4) + aoff8) =
          __builtin_bit_cast(uint2, bv);
    }
#pragma unroll
    for (int j = 0; j < 4; ++j) {
      int n = j * 32 + wn;
      *(uint4*)(smc + 32768 + n * 256 + (((wc >> 4) ^ (n & 7)) << 4)) = wS[j];
    }
  };

  issue(0);
  asm volatile("s_waitcnt vmcnt(0)" ::: "memory");
  writeLds();
  __syncthreads();

  const int rowA = wm * 32 + l31;
  const int swA = rowA & 7;
  const int n0 = nh * 64 + l31;

  for (int kt = 0; kt < 8; ++kt) {
    if (kt + 1 < 8) issue(kt + 1);   // overlap HBM latency with compute
    __builtin_amdgcn_s_setprio(1);
#pragma unroll
    for (int sub = 0; sub < 4; ++sub) {
#pragma unroll
      for (int db = 0; db < 2; ++db) {
        const int slot = sub * 4 + db * 2 + h;
        bf16x8 af = *(const bf16x8*)(smc + rowA * 256 + ((slot ^ swA) << 4));
#pragma unroll
        for (int nf = 0; nf < 2; ++nf) {
          int n = n0 + nf * 32;
          bf16x8 wf = *(const bf16x8*)(smc + 32768 + n * 256 + ((slot ^ (n & 7)) << 4));
          acc[nf] = mfma32(af, wf, acc[nf]);
        }
      }
    }
    __builtin_amdgcn_s_setprio(0);
    __builtin_amdgcn_s_barrier();     // all waves done reading tile kt
    if (kt + 1 < 8) {
      asm volatile("s_waitcnt vmcnt(0)" ::: "memory");
      writeLds();
      asm volatile("s_waitcnt lgkmcnt(0)" ::: "memory");
    }
    __builtin_amdgcn_s_barrier();     // tile kt+1 visible
  }

  // ---- epilogue (structure WRITE_SIZE-validated in R4; reindexed for 512 thr) ----
  if (ty < 2) {
    constexpr int RS = 264;
#pragma unroll
    for (int nf = 0; nf < 2; ++nf)
#pragma unroll
      for (int r = 0; r < 16; ++r) {
        int rowL = wm * 32 + (r & 3) + 8 * (r >> 2) + 4 * h;
        *(bf16_t*)(smc + rowL * RS + (nh * 64 + nf * 32 + l31) * 2) = (bf16_t)acc[nf][r];
      }
    __syncthreads();
    bf16_t* O = (ty == 0) ? Qp : Kp;
    char* obase = (char*)(O + (size_t)(bm * 128) * 128);
#pragma unroll
    for (int ii = 0; ii < 4; ++ii) {
      int g = ii * 512 + tid;          // 2048 x 16B chunks
      int rr = g >> 4, ch = g & 15;
      uint4 vv = *(const uint4*)(smc + rr * RS + ch * 16);
      *(uint4*)(obase + rr * 256 + ch * 16) = vv;
    }
  } else {
    // transpose 128x128 tile through LDS, write Vt[b][n][m] coalesced
#pragma unroll
    for (int nf = 0; nf < 2; ++nf)
#pragma unroll
      for (int rg = 0; rg < 4; ++rg) {
        int n = nh * 64 + nf * 32 + l31;
        bf16x4v bv;
#pragma unroll
        for (int j = 0; j < 4; ++j) bv[j] = (bf16_t)acc[nf][rg * 4 + j];
        int byt = n * 256 + ((((wm << 2) | rg) ^ (n & 7)) << 4) + 8 * h;
        *(uint2*)(smc + byt) = __builtin_bit_cast(uint2, bv);
      }
    __syncthreads();
    const int bb = bm >> 5;
    const int r0v = (bm & 31) * 128;
#pragma unroll
    for (int i = 0; i < 4; ++i) {
      int c = tid + 512 * i;
      int n = c >> 4, sl = c & 15;
      uint4 vv = *(const uint4*)(smc + n * 256 + ((sl ^ (n & 7)) << 4));
      *(uint4*)(Vt + (size_t)(bb * 128 + n) * 4096 + r0v + sl * 8) = vv;
    }
  }
}

// Build PV A-fragment in-register: 4x v_cvt_pk_bf16_f32 + 4x shfl_xor(32).
template <int B0>
static __device__ __forceinline__ bf16x8 build_pf(const f32x16& s, int h) {
  unsigned c0, c1, c2, c3;
  asm("v_cvt_pk_bf16_f32 %0, %1, %2" : "=v"(c0) : "v"(s[B0 + 0]), "v"(s[B0 + 1]));
  asm("v_cvt_pk_bf16_f32 %0, %1, %2" : "=v"(c1) : "v"(s[B0 + 2]), "v"(s[B0 + 3]));
  asm("v_cvt_pk_bf16_f32 %0, %1, %2" : "=v"(c2) : "v"(s[B0 + 4]), "v"(s[B0 + 5]));
  asm("v_cvt_pk_bf16_f32 %0, %1, %2" : "=v"(c3) : "v"(s[B0 + 6]), "v"(s[B0 + 7]));
  unsigned x0 = (unsigned)__shfl_xor((int)c0, 32);
  unsigned x1 = (unsigned)__shfl_xor((int)c1, 32);
  unsigned x2 = (unsigned)__shfl_xor((int)c2, 32);
  unsigned x3 = (unsigned)__shfl_xor((int)c3, 32);
  uint4 u;
  u.x = h ? x2 : c0;
  u.y = h ? x3 : c1;
  u.z = h ? c2 : x0;
  u.w = h ? c3 : x1;
  return __builtin_bit_cast(bf16x8, u);
}

// Flash attention (unchanged from R5: gld_lds dbuf, counted vmcnt(8)).
template <int SPLIT>
__global__ __launch_bounds__(256, 2) void attn_kernel(
    const bf16_t* __restrict__ Qp, const bf16_t* __restrict__ Kp,
    const bf16_t* __restrict__ Vt, float* __restrict__ out,
    float* __restrict__ Opart, float* __restrict__ Mpart, float* __restrict__ Lpart) {
  __shared__ __align__(16) char smc[65536];  // 2 x (K 16K | V 16K)
  const int tid = threadIdx.x;
  const int lane = tid & 63, w = tid >> 6;
  const int l31 = lane & 31, h = lane >> 5;
  const int bid = blockIdx.x;
  const int b = bid & 7;
  const int qt = (bid >> 3) & 31;
  const int s = bid >> 8;
  const int NT = 64 / SPLIT;
  const float CEXP = CEXP_CONST;
  const int qbase = qt * 128 + w * 32;
  const int sw0 = (l31 ^ (l31 >> 3)) & 7;
  const int sw1 = sw0 ^ 4;

  bf16x8 qf[8];
  const bf16_t* qrow = Qp + (size_t)(b * 4096 + qbase + l31) * 128 + h * 8;
#pragma unroll
  for (int db = 0; db < 8; ++db) qf[db] = *(const bf16x8*)(qrow + db * 16);

  int swv[4];
#pragma unroll
  for (int nf = 0; nf < 4; ++nf) swv[nf] = (l31 & 7) ^ ((4 * nf + (l31 >> 3)) & 7);

  const int rl = lane >> 4, slK = lane & 15;
  const int dl = lane >> 3, slV = lane & 7;
  int koff[4], voff[4];
#pragma unroll
  for (int i = 0; i < 4; ++i) {
    int r = w * 16 + i * 4 + rl;
    int swr = (r ^ (r >> 3)) & 7;
    koff[i] = r * 256 + (((slK & 8) | ((slK & 7) ^ swr)) << 4);
    int d = w * 32 + i * 8 + dl;
    int swd = (d ^ (d >> 3)) & 7;
    voff[i] = d * 8192 + ((slV ^ swd) << 4);
  }
  const char* kpb = (const char*)Kp + (size_t)b * 1048576 + (size_t)s * NT * 16384;
  const char* vpb = (const char*)Vt + (size_t)b * 1048576 + (size_t)s * NT * 128;

  f32x16 oacc[4];
#pragma unroll
  for (int nf = 0; nf < 4; ++nf)
#pragma unroll
    for (int r = 0; r < 16; ++r) oacc[nf][r] = 0.0f;
  float m_run = -3.0e38f, lacc = 0.0f;

  auto stage = [&](int tt, int bufb) {
    const char* kb = kpb + (size_t)tt * 16384;
    const char* vb = vpb + (size_t)tt * 128;
    char* lk = smc + bufb + w * 4096;
    char* lv = smc + bufb + 16384 + w * 4096;
#pragma unroll
    for (int i = 0; i < 4; ++i) {
      gld_lds16(kb + koff[i], lk + i * 1024);
      gld_lds16(vb + voff[i], lv + i * 1024);
    }
  };

  stage(0, 0);
  stage(1, 32768);

  for (int t = 0; t < NT; ++t) {
    asm volatile("s_waitcnt vmcnt(8)" ::: "memory");
    __builtin_amdgcn_s_barrier();
    const char* kb = smc + (t & 1) * 32768;
    const char* vb = kb + 16384;

    f32x16 s0, s1;
#pragma unroll
    for (int i = 0; i < 16; ++i) { s0[i] = 0.0f; s1[i] = 0.0f; }
    __builtin_amdgcn_s_setprio(1);
#pragma unroll
    for (int db = 0; db < 8; ++db) {
      const int q = 2 * db + h;
      bf16x8 k0 = *(const bf16x8*)(kb + l31 * 256 + (((q & 8) | ((q & 7) ^ sw0)) << 4));
      bf16x8 k1 = *(const bf16x8*)(kb + (32 + l31) * 256 + (((q & 8) | ((q & 7) ^ sw1)) << 4));
      s0 = mfma32(k0, qf[db], s0);
      s1 = mfma32(k1, qf[db], s1);
    }
    __builtin_amdgcn_s_setprio(0);

    float tmax = fmaxf(s0[0], s1[0]);
#pragma unroll
    for (int i = 1; i < 16; ++i) tmax = fmaxf(tmax, fmaxf(s0[i], s1[i]));
    tmax = fmaxf(tmax, __shfl_xor(tmax, 32));
    if (__any(tmax > m_run + 62.0f)) {
      float mnew = fmaxf(m_run, tmax);
      float fac = exp2f((m_run - mnew) * CEXP);
      m_run = mnew;
      lacc *= fac;
#pragma unroll
      for (int r = 0; r < 16; ++r) {
        float fr = __shfl(fac, (r & 3) + 8 * (r >> 2) + 4 * h);
#pragma unroll
        for (int nf = 0; nf < 4; ++nf) oacc[nf][r] *= fr;
      }
    }
    const float mc = m_run * CEXP;
#pragma unroll
    for (int i = 0; i < 16; ++i) s0[i] = exp2f(fmaf(s0[i], CEXP, -mc));
#pragma unroll
    for (int i = 0; i < 16; ++i) s1[i] = exp2f(fmaf(s1[i], CEXP, -mc));
    float a0 = 0.f, a1 = 0.f, a2 = 0.f, a3 = 0.f;
#pragma unroll
    for (int i = 0; i < 16; i += 4) {
      a0 += s0[i] + s1[i];         a1 += s0[i + 1] + s1[i + 1];
      a2 += s0[i + 2] + s1[i + 2]; a3 += s0[i + 3] + s1[i + 3];
    }
    lacc += (a0 + a1) + (a2 + a3);

    __builtin_amdgcn_s_setprio(1);
    {
      bf16x8 pf = build_pf<0>(s0, h);
#pragma unroll
      for (int nf = 0; nf < 4; ++nf) {
        bf16x8 vf = *(const bf16x8*)(vb + (nf * 32 + l31) * 128 + (((0 + h) ^ swv[nf]) << 4));
        oacc[nf] = mfma32(pf, vf, oacc[nf]);
      }
    }
    {
      bf16x8 pf = build_pf<8>(s0, h);
#pragma unroll
      for (int nf = 0; nf < 4; ++nf) {
        bf16x8 vf = *(const bf16x8*)(vb + (nf * 32 + l31) * 128 + (((2 + h) ^ swv[nf]) << 4));
        oacc[nf] = mfma32(pf, vf, oacc[nf]);
      }
    }
    {
      bf16x8 pf = build_pf<0>(s1, h);
#pragma unroll
      for (int nf = 0; nf < 4; ++nf) {
        bf16x8 vf = *(const bf16x8*)(vb + (nf * 32 + l31) * 128 + (((4 + h) ^ swv[nf]) << 4));
        oacc[nf] = mfma32(pf, vf, oacc[nf]);
      }
    }
    {
      bf16x8 pf = build_pf<8>(s1, h);
#pragma unroll
      for (int nf = 0; nf < 4; ++nf) {
        bf16x8 vf = *(const bf16x8*)(vb + (nf * 32 + l31) * 128 + (((6 + h) ^ swv[nf]) << 4));
        oacc[nf] = mfma32(pf, vf, oacc[nf]);
      }
    }
    __builtin_amdgcn_s_setprio(0);

    __builtin_amdgcn_s_barrier();
    stage((t + 2) & (NT - 1), (t & 1) * 32768);
  }
  asm volatile("s_waitcnt vmcnt(0)" ::: "memory");

  lacc += __shfl_xor(lacc, 32);
  if (SPLIT == 1) {
    const float inv = 1.0f / lacc;
    float* ob = out + (size_t)(b * 4096 + qbase) * 128;
#pragma unroll
    for (int r = 0; r < 16; ++r) {
      const int rowD = (r & 3) + 8 * (r >> 2) + 4 * h;
      float ir = __shfl(inv, rowD);
#pragma unroll
      for (int nf = 0; nf < 4; ++nf)
        ob[(size_t)rowD * 128 + nf * 32 + l31] = oacc[nf][r] * ir;
    }
  } else {
    const int pb = s * 256 + b * 32 + qt;
    if (lane < 32) {
      Mpart[pb * 128 + w * 32 + l31] = m_run;
      Lpart[pb * 128 + w * 32 + l31] = lacc;
    }
    float* ob = Opart + ((size_t)pb * 128 + w * 32) * 128;
#pragma unroll
    for (int r = 0; r < 16; ++r) {
      const int rowD = (r & 3) + 8 * (r >> 2) + 4 * h;
#pragma unroll
      for (int nf = 0; nf < 4; ++nf)
        ob[(size_t)rowD * 128 + nf * 32 + l31] = oacc[nf][r];
    }
  }
}

// Combine 2 split partials. grid 4096 x 256: 8 rows/block, 32 lanes/row (float4).
__global__ __launch_bounds__(256) void combine_kernel(
    const float* __restrict__ Opart, const float* __restrict__ Mpart,
    const float* __restrict__ Lpart, float* __restrict__ out) {
  const int g = blockIdx.x * 8 + (threadIdx.x >> 5);
  const int lane32 = threadIdx.x & 31;
  const int b = g >> 12;
  const int pos = g & 4095;
  const int qt = pos >> 7;
  const int row = pos & 127;
  const int i0 = (b * 32 + qt) * 128 + row;
  const int i1 = (256 + b * 32 + qt) * 128 + row;
  const float m0 = Mpart[i0], m1 = Mpart[i1];
  const float l0 = Lpart[i0], l1 = Lpart[i1];
  const float m = fmaxf(m0, m1);
  const float w0 = exp2f((m0 - m) * CEXP_CONST);
  const float w1 = exp2f((m1 - m) * CEXP_CONST);
  const float inv = 1.0f / (w0 * l0 + w1 * l1);
  const float4 o0 = *(const float4*)(Opart + (size_t)i0 * 128 + lane32 * 4);
  const float4 o1 = *(const float4*)(Opart + (size_t)i1 * 128 + lane32 * 4);
  float4 o;
  o.x = (w0 * o0.x + w1 * o1.x) * inv;
  o.y = (w0 * o0.y + w1 * o1.y) * inv;
  o.z = (w0 * o0.z + w1 * o1.z) * inv;
  o.w = (w0 * o0.w + w1 * o1.w) * inv;
  *(float4*)(out + (size_t)g * 128 + lane32 * 4) = o;
}

extern "C" void kernel_launch(void* const* d_in, const int* in_sizes, int n_in,
                              void* d_out, int out_size, void* d_ws, size_t ws_size,
                              hipStream_t stream) {
  const float* q  = (const float*)d_in[0];
  const float* k  = (const float*)d_in[1];
  const float* v  = (const float*)d_in[2];
  const float* Wq = (const float*)d_in[3];
  const float* Wk = (const float*)d_in[4];
  const float* Wv = (const float*)d_in[5];
  float* out = (float*)d_out;
  char* ws = (char*)d_ws;
  bf16_t* Wt = (bf16_t*)(ws);
  bf16_t* Qp = (bf16_t*)(ws + (size_t)(1u << 20));
  bf16_t* Kp = (bf16_t*)(ws + (size_t)(9u << 20));
  bf16_t* Vt = (bf16_t*)(ws + (size_t)(17u << 20));
  float* Opart = (float*)(ws + (size_t)(32u << 20));
  float* Mpart = (float*)(ws + (size_t)(64u << 20));
  float* Lpart = (float*)(ws + (size_t)(64u << 20) + (256u << 10));

  hipLaunchKernelGGL(wt_kernel, dim3(1536), dim3(256), 0, stream, Wq, Wk, Wv, Wt);
  hipLaunchKernelGGL(proj_kernel, dim3(256, 3), dim3(512), 0, stream, q, k, v, Wt, Qp, Kp, Vt);

  if (ws_size >= ((size_t)65 << 20)) {
    hipLaunchKernelGGL((attn_kernel<2>), dim3(512), dim3(256), 0, stream,
                       Qp, Kp, Vt, out, Opart, Mpart, Lpart);
    hipLaunchKernelGGL(combine_kernel, dim3(4096), dim3(256), 0, stream,
                       Opart, Mpart, Lpart, out);
  } else {
    hipLaunchKernelGGL((attn_kernel<1>), dim3(256), dim3(256), 0, stream,
                       Qp, Kp, Vt, out, Opart, Mpart, Lpart);
  }
}

// Round 8
// 230.832 us; speedup vs baseline: 1.1481x; 1.0297x over previous
//
#include <hip/hip_runtime.h>
#include <cstdint>
#include <cstddef>

typedef __bf16 bf16_t;
typedef __bf16 bf16x8 __attribute__((ext_vector_type(8)));
typedef __bf16 bf16x4v __attribute__((ext_vector_type(4)));
typedef float f32x16 __attribute__((ext_vector_type(16)));

static __device__ __forceinline__ f32x16 mfma32(bf16x8 a, bf16x8 b, f32x16 c) {
  return __builtin_amdgcn_mfma_f32_32x32x16_bf16(a, b, c, 0, 0, 0);
}

// Direct global->LDS DMA, 16B per lane (attn kernel only).
static __device__ __forceinline__ void gld_lds16(const void* g, void* l) {
  __builtin_amdgcn_global_load_lds(
      (const __attribute__((address_space(1))) unsigned int*)g,
      (__attribute__((address_space(3))) unsigned int*)l, 16, 0, 0);
}

#define CEXP_CONST 0.12754582f  // (1/sqrt(128)) * log2(e)

// ---------------------------------------------------------------------------
// Workspace layout (bytes):
//   [0, 768K)        Wt    bf16 [3][128][1024]
//   [1M, 9M)         Qp    bf16 [8][4096][128]
//   [9M, 17M)        Kp    bf16 [8][4096][128]
//   [17M, 25M)       Vt    bf16 [8][128][4096]
//   [32M, 64M)       Opart f32  [2*256][128][128]
//   [64M, +256K)     Mpart f32  [2*256*128]
//   [64M+256K,+256K) Lpart f32  [2*256*128]
// ---------------------------------------------------------------------------

__global__ void wt_kernel(const float* __restrict__ Wq, const float* __restrict__ Wk,
                          const float* __restrict__ Wv, bf16_t* __restrict__ Wt) {
  int t = blockIdx.x * 256 + threadIdx.x;
  int tensor = t >> 17;
  int r = t & 131071;
  int kk = r >> 7, n = r & 127;
  const float* W = tensor == 0 ? Wq : (tensor == 1 ? Wk : Wv);
  Wt[(size_t)tensor * 131072 + (size_t)n * 1024 + kk] = (bf16_t)W[(size_t)kk * 128 + n];
}

// X[32768,1024]f32 @ W[1024,128] -> bf16.
// R8 experiment: per-block ROTATED k-tile order (kr = (kt+bm)&7) so concurrent
// blocks read DIFFERENT 512B column classes of the 4KB-stride A matrix ->
// spreads requests across HBM channel/bank classes. Accumulation over k is
// order-independent, so this is math-neutral. Everything else identical to R7.
// ty: 0=Q, 1=K (row-major out), 2=V (transposed out).
__global__ __launch_bounds__(512, 2) void proj_kernel(
    const float* __restrict__ xq, const float* __restrict__ xk, const float* __restrict__ xv,
    const bf16_t* __restrict__ WtAll,
    bf16_t* __restrict__ Qp, bf16_t* __restrict__ Kp, bf16_t* __restrict__ Vt) {
  // A: [0,32K) [128 m][256B k-swz]; W: [32K,64K) [128 n][256B k-swz].
  __shared__ __align__(16) char smc[65536];
  const int tid = threadIdx.x;
  const int ty = blockIdx.y;
  const int bm = blockIdx.x;
  const float* X = (ty == 0) ? xq : (ty == 1) ? xk : xv;
  const bf16_t* Wg = WtAll + (size_t)ty * 131072;
  const int lane = tid & 63;
  const int w = tid >> 6;          // wave 0..7
  const int l31 = lane & 31, h = lane >> 5;
  const int wm = w & 3, nh = w >> 2;

  f32x16 acc[2];
#pragma unroll
  for (int nf = 0; nf < 2; ++nf)
#pragma unroll
    for (int r = 0; r < 16; ++r) acc[nf][r] = 0.0f;

  // A staging: j<8: row = j*16 + (tid>>5), colb = (tid&31)*16  (512B row-chunks)
  const int arow = tid >> 5;                 // 0..15
  const int acolb = (tid & 31) * 16;
  const char* aG = (const char*)X + (size_t)(bm * 128) * 4096 + acolb;
  const int aslot = (tid & 31) >> 1, aoff8 = (tid & 1) * 8;
  // W staging: j<4: n = j*32 + (tid>>4), c = (tid&15)*16 (256B row-chunks)
  const int wn = tid >> 4;                   // 0..31
  const int wc = (tid & 15) * 16;
  const char* wG = (const char*)Wg + (size_t)wn * 2048 + wc;

  float4 aS[8];
  uint4 wS[4];

  auto issue = [&](int kt) {
    const int kr = (kt + bm) & 7;   // per-block rotated k order (channel spread)
#pragma unroll
    for (int j = 0; j < 8; ++j)
      aS[j] = *(const float4*)(aG + (size_t)(j * 16 + arow) * 4096 + kr * 512);
#pragma unroll
    for (int j = 0; j < 4; ++j)
      wS[j] = *(const uint4*)(wG + (size_t)j * 65536 + kr * 256);
  };
  auto writeLds = [&]() {
#pragma unroll
    for (int j = 0; j < 8; ++j) {
      int row = j * 16 + arow;
      bf16x4v bv;
      bv[0] = (bf16_t)aS[j].x; bv[1] = (bf16_t)aS[j].y;
      bv[2] = (bf16_t)aS[j].z; bv[3] = (bf16_t)aS[j].w;
      *(uint2*)(smc + row * 256 + ((aslot ^ (row & 7)) << 4) + aoff8) =
          __builtin_bit_cast(uint2, bv);
    }
#pragma unroll
    for (int j = 0; j < 4; ++j) {
      int n = j * 32 + wn;
      *(uint4*)(smc + 32768 + n * 256 + (((wc >> 4) ^ (n & 7)) << 4)) = wS[j];
    }
  };

  issue(0);
  asm volatile("s_waitcnt vmcnt(0)" ::: "memory");
  writeLds();
  __syncthreads();

  const int rowA = wm * 32 + l31;
  const int swA = rowA & 7;
  const int n0 = nh * 64 + l31;

  for (int kt = 0; kt < 8; ++kt) {
    if (kt + 1 < 8) issue(kt + 1);   // overlap HBM latency with compute
    __builtin_amdgcn_s_setprio(1);
#pragma unroll
    for (int sub = 0; sub < 4; ++sub) {
#pragma unroll
      for (int db = 0; db < 2; ++db) {
        const int slot = sub * 4 + db * 2 + h;
        bf16x8 af = *(const bf16x8*)(smc + rowA * 256 + ((slot ^ swA) << 4));
#pragma unroll
        for (int nf = 0; nf < 2; ++nf) {
          int n = n0 + nf * 32;
          bf16x8 wf = *(const bf16x8*)(smc + 32768 + n * 256 + ((slot ^ (n & 7)) << 4));
          acc[nf] = mfma32(af, wf, acc[nf]);
        }
      }
    }
    __builtin_amdgcn_s_setprio(0);
    __builtin_amdgcn_s_barrier();     // all waves done reading tile kt
    if (kt + 1 < 8) {
      asm volatile("s_waitcnt vmcnt(0)" ::: "memory");
      writeLds();
      asm volatile("s_waitcnt lgkmcnt(0)" ::: "memory");
    }
    __builtin_amdgcn_s_barrier();     // tile kt+1 visible
  }

  // ---- epilogue (structure WRITE_SIZE-validated in R4; reindexed for 512 thr) ----
  if (ty < 2) {
    constexpr int RS = 264;
#pragma unroll
    for (int nf = 0; nf < 2; ++nf)
#pragma unroll
      for (int r = 0; r < 16; ++r) {
        int rowL = wm * 32 + (r & 3) + 8 * (r >> 2) + 4 * h;
        *(bf16_t*)(smc + rowL * RS + (nh * 64 + nf * 32 + l31) * 2) = (bf16_t)acc[nf][r];
      }
    __syncthreads();
    bf16_t* O = (ty == 0) ? Qp : Kp;
    char* obase = (char*)(O + (size_t)(bm * 128) * 128);
#pragma unroll
    for (int ii = 0; ii < 4; ++ii) {
      int g = ii * 512 + tid;          // 2048 x 16B chunks
      int rr = g >> 4, ch = g & 15;
      uint4 vv = *(const uint4*)(smc + rr * RS + ch * 16);
      *(uint4*)(obase + rr * 256 + ch * 16) = vv;
    }
  } else {
    // transpose 128x128 tile through LDS, write Vt[b][n][m] coalesced
#pragma unroll
    for (int nf = 0; nf < 2; ++nf)
#pragma unroll
      for (int rg = 0; rg < 4; ++rg) {
        int n = nh * 64 + nf * 32 + l31;
        bf16x4v bv;
#pragma unroll
        for (int j = 0; j < 4; ++j) bv[j] = (bf16_t)acc[nf][rg * 4 + j];
        int byt = n * 256 + ((((wm << 2) | rg) ^ (n & 7)) << 4) + 8 * h;
        *(uint2*)(smc + byt) = __builtin_bit_cast(uint2, bv);
      }
    __syncthreads();
    const int bb = bm >> 5;
    const int r0v = (bm & 31) * 128;
#pragma unroll
    for (int i = 0; i < 4; ++i) {
      int c = tid + 512 * i;
      int n = c >> 4, sl = c & 15;
      uint4 vv = *(const uint4*)(smc + n * 256 + ((sl ^ (n & 7)) << 4));
      *(uint4*)(Vt + (size_t)(bb * 128 + n) * 4096 + r0v + sl * 8) = vv;
    }
  }
}

// Build PV A-fragment in-register: 4x v_cvt_pk_bf16_f32 + 4x shfl_xor(32).
template <int B0>
static __device__ __forceinline__ bf16x8 build_pf(const f32x16& s, int h) {
  unsigned c0, c1, c2, c3;
  asm("v_cvt_pk_bf16_f32 %0, %1, %2" : "=v"(c0) : "v"(s[B0 + 0]), "v"(s[B0 + 1]));
  asm("v_cvt_pk_bf16_f32 %0, %1, %2" : "=v"(c1) : "v"(s[B0 + 2]), "v"(s[B0 + 3]));
  asm("v_cvt_pk_bf16_f32 %0, %1, %2" : "=v"(c2) : "v"(s[B0 + 4]), "v"(s[B0 + 5]));
  asm("v_cvt_pk_bf16_f32 %0, %1, %2" : "=v"(c3) : "v"(s[B0 + 6]), "v"(s[B0 + 7]));
  unsigned x0 = (unsigned)__shfl_xor((int)c0, 32);
  unsigned x1 = (unsigned)__shfl_xor((int)c1, 32);
  unsigned x2 = (unsigned)__shfl_xor((int)c2, 32);
  unsigned x3 = (unsigned)__shfl_xor((int)c3, 32);
  uint4 u;
  u.x = h ? x2 : c0;
  u.y = h ? x3 : c1;
  u.z = h ? c2 : x0;
  u.w = h ? c3 : x1;
  return __builtin_bit_cast(bf16x8, u);
}

// Flash attention (unchanged from R5: gld_lds dbuf, counted vmcnt(8)).
template <int SPLIT>
__global__ __launch_bounds__(256, 2) void attn_kernel(
    const bf16_t* __restrict__ Qp, const bf16_t* __restrict__ Kp,
    const bf16_t* __restrict__ Vt, float* __restrict__ out,
    float* __restrict__ Opart, float* __restrict__ Mpart, float* __restrict__ Lpart) {
  __shared__ __align__(16) char smc[65536];  // 2 x (K 16K | V 16K)
  const int tid = threadIdx.x;
  const int lane = tid & 63, w = tid >> 6;
  const int l31 = lane & 31, h = lane >> 5;
  const int bid = blockIdx.x;
  const int b = bid & 7;
  const int qt = (bid >> 3) & 31;
  const int s = bid >> 8;
  const int NT = 64 / SPLIT;
  const float CEXP = CEXP_CONST;
  const int qbase = qt * 128 + w * 32;
  const int sw0 = (l31 ^ (l31 >> 3)) & 7;
  const int sw1 = sw0 ^ 4;

  bf16x8 qf[8];
  const bf16_t* qrow = Qp + (size_t)(b * 4096 + qbase + l31) * 128 + h * 8;
#pragma unroll
  for (int db = 0; db < 8; ++db) qf[db] = *(const bf16x8*)(qrow + db * 16);

  int swv[4];
#pragma unroll
  for (int nf = 0; nf < 4; ++nf) swv[nf] = (l31 & 7) ^ ((4 * nf + (l31 >> 3)) & 7);

  const int rl = lane >> 4, slK = lane & 15;
  const int dl = lane >> 3, slV = lane & 7;
  int koff[4], voff[4];
#pragma unroll
  for (int i = 0; i < 4; ++i) {
    int r = w * 16 + i * 4 + rl;
    int swr = (r ^ (r >> 3)) & 7;
    koff[i] = r * 256 + (((slK & 8) | ((slK & 7) ^ swr)) << 4);
    int d = w * 32 + i * 8 + dl;
    int swd = (d ^ (d >> 3)) & 7;
    voff[i] = d * 8192 + ((slV ^ swd) << 4);
  }
  const char* kpb = (const char*)Kp + (size_t)b * 1048576 + (size_t)s * NT * 16384;
  const char* vpb = (const char*)Vt + (size_t)b * 1048576 + (size_t)s * NT * 128;

  f32x16 oacc[4];
#pragma unroll
  for (int nf = 0; nf < 4; ++nf)
#pragma unroll
    for (int r = 0; r < 16; ++r) oacc[nf][r] = 0.0f;
  float m_run = -3.0e38f, lacc = 0.0f;

  auto stage = [&](int tt, int bufb) {
    const char* kb = kpb + (size_t)tt * 16384;
    const char* vb = vpb + (size_t)tt * 128;
    char* lk = smc + bufb + w * 4096;
    char* lv = smc + bufb + 16384 + w * 4096;
#pragma unroll
    for (int i = 0; i < 4; ++i) {
      gld_lds16(kb + koff[i], lk + i * 1024);
      gld_lds16(vb + voff[i], lv + i * 1024);
    }
  };

  stage(0, 0);
  stage(1, 32768);

  for (int t = 0; t < NT; ++t) {
    asm volatile("s_waitcnt vmcnt(8)" ::: "memory");
    __builtin_amdgcn_s_barrier();
    const char* kb = smc + (t & 1) * 32768;
    const char* vb = kb + 16384;

    f32x16 s0, s1;
#pragma unroll
    for (int i = 0; i < 16; ++i) { s0[i] = 0.0f; s1[i] = 0.0f; }
    __builtin_amdgcn_s_setprio(1);
#pragma unroll
    for (int db = 0; db < 8; ++db) {
      const int q = 2 * db + h;
      bf16x8 k0 = *(const bf16x8*)(kb + l31 * 256 + (((q & 8) | ((q & 7) ^ sw0)) << 4));
      bf16x8 k1 = *(const bf16x8*)(kb + (32 + l31) * 256 + (((q & 8) | ((q & 7) ^ sw1)) << 4));
      s0 = mfma32(k0, qf[db], s0);
      s1 = mfma32(k1, qf[db], s1);
    }
    __builtin_amdgcn_s_setprio(0);

    float tmax = fmaxf(s0[0], s1[0]);
#pragma unroll
    for (int i = 1; i < 16; ++i) tmax = fmaxf(tmax, fmaxf(s0[i], s1[i]));
    tmax = fmaxf(tmax, __shfl_xor(tmax, 32));
    if (__any(tmax > m_run + 62.0f)) {
      float mnew = fmaxf(m_run, tmax);
      float fac = exp2f((m_run - mnew) * CEXP);
      m_run = mnew;
      lacc *= fac;
#pragma unroll
      for (int r = 0; r < 16; ++r) {
        float fr = __shfl(fac, (r & 3) + 8 * (r >> 2) + 4 * h);
#pragma unroll
        for (int nf = 0; nf < 4; ++nf) oacc[nf][r] *= fr;
      }
    }
    const float mc = m_run * CEXP;
#pragma unroll
    for (int i = 0; i < 16; ++i) s0[i] = exp2f(fmaf(s0[i], CEXP, -mc));
#pragma unroll
    for (int i = 0; i < 16; ++i) s1[i] = exp2f(fmaf(s1[i], CEXP, -mc));
    float a0 = 0.f, a1 = 0.f, a2 = 0.f, a3 = 0.f;
#pragma unroll
    for (int i = 0; i < 16; i += 4) {
      a0 += s0[i] + s1[i];         a1 += s0[i + 1] + s1[i + 1];
      a2 += s0[i + 2] + s1[i + 2]; a3 += s0[i + 3] + s1[i + 3];
    }
    lacc += (a0 + a1) + (a2 + a3);

    __builtin_amdgcn_s_setprio(1);
    {
      bf16x8 pf = build_pf<0>(s0, h);
#pragma unroll
      for (int nf = 0; nf < 4; ++nf) {
        bf16x8 vf = *(const bf16x8*)(vb + (nf * 32 + l31) * 128 + (((0 + h) ^ swv[nf]) << 4));
        oacc[nf] = mfma32(pf, vf, oacc[nf]);
      }
    }
    {
      bf16x8 pf = build_pf<8>(s0, h);
#pragma unroll
      for (int nf = 0; nf < 4; ++nf) {
        bf16x8 vf = *(const bf16x8*)(vb + (nf * 32 + l31) * 128 + (((2 + h) ^ swv[nf]) << 4));
        oacc[nf] = mfma32(pf, vf, oacc[nf]);
      }
    }
    {
      bf16x8 pf = build_pf<0>(s1, h);
#pragma unroll
      for (int nf = 0; nf < 4; ++nf) {
        bf16x8 vf = *(const bf16x8*)(vb + (nf * 32 + l31) * 128 + (((4 + h) ^ swv[nf]) << 4));
        oacc[nf] = mfma32(pf, vf, oacc[nf]);
      }
    }
    {
      bf16x8 pf = build_pf<8>(s1, h);
#pragma unroll
      for (int nf = 0; nf < 4; ++nf) {
        bf16x8 vf = *(const bf16x8*)(vb + (nf * 32 + l31) * 128 + (((6 + h) ^ swv[nf]) << 4));
        oacc[nf] = mfma32(pf, vf, oacc[nf]);
      }
    }
    __builtin_amdgcn_s_setprio(0);

    __builtin_amdgcn_s_barrier();
    stage((t + 2) & (NT - 1), (t & 1) * 32768);
  }
  asm volatile("s_waitcnt vmcnt(0)" ::: "memory");

  lacc += __shfl_xor(lacc, 32);
  if (SPLIT == 1) {
    const float inv = 1.0f / lacc;
    float* ob = out + (size_t)(b * 4096 + qbase) * 128;
#pragma unroll
    for (int r = 0; r < 16; ++r) {
      const int rowD = (r & 3) + 8 * (r >> 2) + 4 * h;
      float ir = __shfl(inv, rowD);
#pragma unroll
      for (int nf = 0; nf < 4; ++nf)
        ob[(size_t)rowD * 128 + nf * 32 + l31] = oacc[nf][r] * ir;
    }
  } else {
    const int pb = s * 256 + b * 32 + qt;
    if (lane < 32) {
      Mpart[pb * 128 + w * 32 + l31] = m_run;
      Lpart[pb * 128 + w * 32 + l31] = lacc;
    }
    float* ob = Opart + ((size_t)pb * 128 + w * 32) * 128;
#pragma unroll
    for (int r = 0; r < 16; ++r) {
      const int rowD = (r & 3) + 8 * (r >> 2) + 4 * h;
#pragma unroll
      for (int nf = 0; nf < 4; ++nf)
        ob[(size_t)rowD * 128 + nf * 32 + l31] = oacc[nf][r];
    }
  }
}

// Combine 2 split partials. grid 4096 x 256: 8 rows/block, 32 lanes/row (float4).
__global__ __launch_bounds__(256) void combine_kernel(
    const float* __restrict__ Opart, const float* __restrict__ Mpart,
    const float* __restrict__ Lpart, float* __restrict__ out) {
  const int g = blockIdx.x * 8 + (threadIdx.x >> 5);
  const int lane32 = threadIdx.x & 31;
  const int b = g >> 12;
  const int pos = g & 4095;
  const int qt = pos >> 7;
  const int row = pos & 127;
  const int i0 = (b * 32 + qt) * 128 + row;
  const int i1 = (256 + b * 32 + qt) * 128 + row;
  const float m0 = Mpart[i0], m1 = Mpart[i1];
  const float l0 = Lpart[i0], l1 = Lpart[i1];
  const float m = fmaxf(m0, m1);
  const float w0 = exp2f((m0 - m) * CEXP_CONST);
  const float w1 = exp2f((m1 - m) * CEXP_CONST);
  const float inv = 1.0f / (w0 * l0 + w1 * l1);
  const float4 o0 = *(const float4*)(Opart + (size_t)i0 * 128 + lane32 * 4);
  const float4 o1 = *(const float4*)(Opart + (size_t)i1 * 128 + lane32 * 4);
  float4 o;
  o.x = (w0 * o0.x + w1 * o1.x) * inv;
  o.y = (w0 * o0.y + w1 * o1.y) * inv;
  o.z = (w0 * o0.z + w1 * o1.z) * inv;
  o.w = (w0 * o0.w + w1 * o1.w) * inv;
  *(float4*)(out + (size_t)g * 128 + lane32 * 4) = o;
}

extern "C" void kernel_launch(void* const* d_in, const int* in_sizes, int n_in,
                              void* d_out, int out_size, void* d_ws, size_t ws_size,
                              hipStream_t stream) {
  const float* q  = (const float*)d_in[0];
  const float* k  = (const float*)d_in[1];
  const float* v  = (const float*)d_in[2];
  const float* Wq = (const float*)d_in[3];
  const float* Wk = (const float*)d_in[4];
  const float* Wv = (const float*)d_in[5];
  float* out = (float*)d_out;
  char* ws = (char*)d_ws;
  bf16_t* Wt = (bf16_t*)(ws);
  bf16_t* Qp = (bf16_t*)(ws + (size_t)(1u << 20));
  bf16_t* Kp = (bf16_t*)(ws + (size_t)(9u << 20));
  bf16_t* Vt = (bf16_t*)(ws + (size_t)(17u << 20));
  float* Opart = (float*)(ws + (size_t)(32u << 20));
  float* Mpart = (float*)(ws + (size_t)(64u << 20));
  float* Lpart = (float*)(ws + (size_t)(64u << 20) + (256u << 10));

  hipLaunchKernelGGL(wt_kernel, dim3(1536), dim3(256), 0, stream, Wq, Wk, Wv, Wt);
  hipLaunchKernelGGL(proj_kernel, dim3(256, 3), dim3(512), 0, stream, q, k, v, Wt, Qp, Kp, Vt);

  if (ws_size >= ((size_t)65 << 20)) {
    hipLaunchKernelGGL((attn_kernel<2>), dim3(512), dim3(256), 0, stream,
                       Qp, Kp, Vt, out, Opart, Mpart, Lpart);
    hipLaunchKernelGGL(combine_kernel, dim3(4096), dim3(256), 0, stream,
                       Opart, Mpart, Lpart, out);
  } else {
    hipLaunchKernelGGL((attn_kernel<1>), dim3(256), dim3(256), 0, stream,
                       Qp, Kp, Vt, out, Opart, Mpart, Lpart);
  }
}

// Round 9
// 220.157 us; speedup vs baseline: 1.2038x; 1.0485x over previous
//
#include <hip/hip_runtime.h>
#include <cstdint>
#include <cstddef>

typedef __bf16 bf16_t;
typedef __bf16 bf16x8 __attribute__((ext_vector_type(8)));
typedef __bf16 bf16x4v __attribute__((ext_vector_type(4)));
typedef float f32x16 __attribute__((ext_vector_type(16)));

static __device__ __forceinline__ f32x16 mfma32(bf16x8 a, bf16x8 b, f32x16 c) {
  return __builtin_amdgcn_mfma_f32_32x32x16_bf16(a, b, c, 0, 0, 0);
}

// Direct global->LDS DMA, 16B per lane.
static __device__ __forceinline__ void gld_lds16(const void* g, void* l) {
  __builtin_amdgcn_global_load_lds(
      (const __attribute__((address_space(1))) unsigned int*)g,
      (__attribute__((address_space(3))) unsigned int*)l, 16, 0, 0);
}

#define CEXP_CONST 0.12754582f  // (1/sqrt(128)) * log2(e)

// ---------------------------------------------------------------------------
// Workspace layout (bytes):
//   [0, 768K)        Wt2   bf16 [3][64 k16][4 nf][2 h][32 l31][8]  (frag-major)
//   [1M, 9M)         Qp    bf16 [8][4096][128]
//   [9M, 17M)        Kp    bf16 [8][4096][128]
//   [17M, 25M)       Vt    bf16 [8][128][4096]
//   [32M, 64M)       Opart f32  [2*256][128][128]
//   [64M, +256K)     Mpart f32  [2*256*128]
//   [64M+256K,+256K) Lpart f32  [2*256*128]
// ---------------------------------------------------------------------------

// W -> fragment-major bf16: Wt2[((k16*4+nf)*2+h)*32+l31][j] = W[k16*16+h*8+j][nf*32+l31]
__global__ void wt_kernel(const float* __restrict__ Wq, const float* __restrict__ Wk,
                          const float* __restrict__ Wv, bf16_t* __restrict__ Wt2) {
  int t = blockIdx.x * 256 + threadIdx.x;   // 0..393215
  int tensor = t >> 17;
  int r = t & 131071;
  int j = r & 7, l31 = (r >> 3) & 31, h = (r >> 8) & 1, nf = (r >> 9) & 3, k16 = (r >> 11) & 63;
  int k = k16 * 16 + h * 8 + j, n = nf * 32 + l31;
  const float* W = tensor == 0 ? Wq : (tensor == 1 ? Wk : Wv);
  Wt2[t] = (bf16_t)W[(size_t)k * 128 + n];
}

// X[32768,1024]f32 @ W[1024,128] -> bf16. BARRIER-FREE K-LOOP:
// each wave free-runs its own pipeline. A: wave-private gld_lds dbuf (source
// pre-swizzled), counted vmcnt(12). W: fragment-major Wt2 read directly from
// L2, 1KB contiguous per instruction. Per-(block,wave) rotated k order.
// ty: 0=Q, 1=K (row-major out), 2=V (transposed out).
__global__ __launch_bounds__(256, 4) void proj_kernel(
    const float* __restrict__ xq, const float* __restrict__ xk, const float* __restrict__ xv,
    const bf16_t* __restrict__ WtAll,
    bf16_t* __restrict__ Qp, bf16_t* __restrict__ Kp, bf16_t* __restrict__ Vt) {
  // [0,32K): 4 waves x (2 bufs x 4KB A-tile [32 rows x 128B, slot^=(row&7)]).
  // Epilogue reuses [0,33792).
  __shared__ __align__(16) char smc[33792];
  const int tid = threadIdx.x;
  const int ty = blockIdx.y;
  const int bm = blockIdx.x;
  const float* X = (ty == 0) ? xq : (ty == 1) ? xk : xv;
  const bf16_t* W2 = WtAll + (size_t)ty * 131072;
  const int lane = tid & 63;
  const int w = tid >> 6;
  const int l31 = lane & 31, h = lane >> 5;

  f32x16 acc[4];
#pragma unroll
  for (int nf = 0; nf < 4; ++nf)
#pragma unroll
    for (int r = 0; r < 16; ++r) acc[nf][r] = 0.0f;

  // A stage source offsets (swizzle on global side; LDS dest linear).
  // Instr i: rows i*8 + (lane>>3), slot lane&7; src slot ^= (row&7)=(lane>>3).
  int aoff[4];
#pragma unroll
  for (int i = 0; i < 4; ++i)
    aoff[i] = (i * 8 + (lane >> 3)) * 4096 + (((lane & 7) ^ (lane >> 3)) << 4);
  const char* aG = (const char*)X + (size_t)(bm * 128 + w * 32) * 4096;
  char* abuf = smc + w * 8192;
  const int asw = l31 & 7;

  // prologue: stage phys(0) into buf0, drain once
  {
    const int kp = (bm + w) & 31;
#pragma unroll
    for (int i = 0; i < 4; ++i) gld_lds16(aG + kp * 128 + aoff[i], abuf + i * 1024);
  }
  asm volatile("s_waitcnt vmcnt(0)" ::: "memory");

  for (int t = 0; t < 32; ++t) {
    // issue next tile's stage (wrap keeps count uniform; 4 wasted loads at end)
    const int kpn = (t + 1 + bm + w) & 31;
    char* nb = abuf + ((t + 1) & 1) * 4096;
    __builtin_amdgcn_sched_barrier(0);
#pragma unroll
    for (int i = 0; i < 4; ++i) gld_lds16(aG + kpn * 128 + aoff[i], nb + i * 1024);
    __builtin_amdgcn_sched_barrier(0);
    // steady state: 12 vm-ops/iter (4 stage + 8 wf); <=12 outstanding ==
    // stage(t) retired, stage(t+1) still in flight.
    asm volatile("s_waitcnt vmcnt(12)" ::: "memory");
    __builtin_amdgcn_sched_barrier(0);

    const char* Ab = abuf + (t & 1) * 4096;
    const int kphys = (t + bm + w) & 31;
    const bf16_t* wfp = W2 + (size_t)(2 * kphys) * 2048 + lane * 8;  // (k16*4+nf)*64*8 elems
#pragma unroll
    for (int ks = 0; ks < 2; ++ks) {
      const int s0 = ks * 4 + h * 2;
      uint4 u0 = *(const uint4*)(Ab + l31 * 128 + ((s0 ^ asw) << 4));
      uint4 u1 = *(const uint4*)(Ab + l31 * 128 + (((s0 + 1) ^ asw) << 4));
      float4 a0 = __builtin_bit_cast(float4, u0);
      float4 a1 = __builtin_bit_cast(float4, u1);
      bf16x8 af;
      af[0] = (bf16_t)a0.x; af[1] = (bf16_t)a0.y; af[2] = (bf16_t)a0.z; af[3] = (bf16_t)a0.w;
      af[4] = (bf16_t)a1.x; af[5] = (bf16_t)a1.y; af[6] = (bf16_t)a1.z; af[7] = (bf16_t)a1.w;
      const bf16_t* wk = wfp + (size_t)ks * 2048;
#pragma unroll
      for (int nf = 0; nf < 4; ++nf) {
        bf16x8 wf = *(const bf16x8*)(wk + (size_t)nf * 512);
        acc[nf] = mfma32(af, wf, acc[nf]);
      }
    }
  }
  asm volatile("s_waitcnt vmcnt(0)" ::: "memory");  // drain wrap loads (LDS reused)
  __syncthreads();

  // ---- epilogue (WRITE_SIZE-validated in R4) ----
  if (ty < 2) {
    constexpr int RS = 264;
#pragma unroll
    for (int nf = 0; nf < 4; ++nf)
#pragma unroll
      for (int r = 0; r < 16; ++r) {
        int rowL = w * 32 + (r & 3) + 8 * (r >> 2) + 4 * h;
        *(bf16_t*)(smc + rowL * RS + (nf * 32 + l31) * 2) = (bf16_t)acc[nf][r];
      }
    __syncthreads();
    bf16_t* O = (ty == 0) ? Qp : Kp;
    char* obase = (char*)(O + (size_t)(bm * 128) * 128);
#pragma unroll
    for (int ii = 0; ii < 8; ++ii) {
      int g = ii * 256 + tid;          // 2048 x 16B chunks
      int rr = g >> 4, ch = g & 15;
      uint4 vv = *(const uint4*)(smc + rr * RS + ch * 16);
      *(uint4*)(obase + rr * 256 + ch * 16) = vv;
    }
  } else {
    // transpose 128x128 tile through LDS, write Vt[b][n][m] coalesced
#pragma unroll
    for (int nf = 0; nf < 4; ++nf)
#pragma unroll
      for (int rg = 0; rg < 4; ++rg) {
        int n = nf * 32 + l31;
        bf16x4v bv;
#pragma unroll
        for (int j = 0; j < 4; ++j) bv[j] = (bf16_t)acc[nf][rg * 4 + j];
        int byt = n * 256 + (((4 * w + rg) ^ (n & 7)) << 4) + 8 * h;
        *(uint2*)(smc + byt) = __builtin_bit_cast(uint2, bv);
      }
    __syncthreads();
    const int bb = bm >> 5;
    const int r0v = (bm & 31) * 128;
#pragma unroll
    for (int i = 0; i < 8; ++i) {
      int c = tid + 256 * i;
      int n = c >> 4, sl = c & 15;
      uint4 vv = *(const uint4*)(smc + n * 256 + ((sl ^ (n & 7)) << 4));
      *(uint4*)(Vt + (size_t)(bb * 128 + n) * 4096 + r0v + sl * 8) = vv;
    }
  }
}

// Build PV A-fragment in-register: 4x v_cvt_pk_bf16_f32 + 4x shfl_xor(32).
template <int B0>
static __device__ __forceinline__ bf16x8 build_pf(const f32x16& s, int h) {
  unsigned c0, c1, c2, c3;
  asm("v_cvt_pk_bf16_f32 %0, %1, %2" : "=v"(c0) : "v"(s[B0 + 0]), "v"(s[B0 + 1]));
  asm("v_cvt_pk_bf16_f32 %0, %1, %2" : "=v"(c1) : "v"(s[B0 + 2]), "v"(s[B0 + 3]));
  asm("v_cvt_pk_bf16_f32 %0, %1, %2" : "=v"(c2) : "v"(s[B0 + 4]), "v"(s[B0 + 5]));
  asm("v_cvt_pk_bf16_f32 %0, %1, %2" : "=v"(c3) : "v"(s[B0 + 6]), "v"(s[B0 + 7]));
  unsigned x0 = (unsigned)__shfl_xor((int)c0, 32);
  unsigned x1 = (unsigned)__shfl_xor((int)c1, 32);
  unsigned x2 = (unsigned)__shfl_xor((int)c2, 32);
  unsigned x3 = (unsigned)__shfl_xor((int)c3, 32);
  uint4 u;
  u.x = h ? x2 : c0;
  u.y = h ? x3 : c1;
  u.z = h ? c2 : x0;
  u.w = h ? c3 : x1;
  return __builtin_bit_cast(bf16x8, u);
}

// Flash attention (unchanged: gld_lds dbuf, counted vmcnt(8)).
template <int SPLIT>
__global__ __launch_bounds__(256, 2) void attn_kernel(
    const bf16_t* __restrict__ Qp, const bf16_t* __restrict__ Kp,
    const bf16_t* __restrict__ Vt, float* __restrict__ out,
    float* __restrict__ Opart, float* __restrict__ Mpart, float* __restrict__ Lpart) {
  __shared__ __align__(16) char smc[65536];  // 2 x (K 16K | V 16K)
  const int tid = threadIdx.x;
  const int lane = tid & 63, w = tid >> 6;
  const int l31 = lane & 31, h = lane >> 5;
  const int bid = blockIdx.x;
  const int b = bid & 7;
  const int qt = (bid >> 3) & 31;
  const int s = bid >> 8;
  const int NT = 64 / SPLIT;
  const float CEXP = CEXP_CONST;
  const int qbase = qt * 128 + w * 32;
  const int sw0 = (l31 ^ (l31 >> 3)) & 7;
  const int sw1 = sw0 ^ 4;

  bf16x8 qf[8];
  const bf16_t* qrow = Qp + (size_t)(b * 4096 + qbase + l31) * 128 + h * 8;
#pragma unroll
  for (int db = 0; db < 8; ++db) qf[db] = *(const bf16x8*)(qrow + db * 16);

  int swv[4];
#pragma unroll
  for (int nf = 0; nf < 4; ++nf) swv[nf] = (l31 & 7) ^ ((4 * nf + (l31 >> 3)) & 7);

  const int rl = lane >> 4, slK = lane & 15;
  const int dl = lane >> 3, slV = lane & 7;
  int koff[4], voff[4];
#pragma unroll
  for (int i = 0; i < 4; ++i) {
    int r = w * 16 + i * 4 + rl;
    int swr = (r ^ (r >> 3)) & 7;
    koff[i] = r * 256 + (((slK & 8) | ((slK & 7) ^ swr)) << 4);
    int d = w * 32 + i * 8 + dl;
    int swd = (d ^ (d >> 3)) & 7;
    voff[i] = d * 8192 + ((slV ^ swd) << 4);
  }
  const char* kpb = (const char*)Kp + (size_t)b * 1048576 + (size_t)s * NT * 16384;
  const char* vpb = (const char*)Vt + (size_t)b * 1048576 + (size_t)s * NT * 128;

  f32x16 oacc[4];
#pragma unroll
  for (int nf = 0; nf < 4; ++nf)
#pragma unroll
    for (int r = 0; r < 16; ++r) oacc[nf][r] = 0.0f;
  float m_run = -3.0e38f, lacc = 0.0f;

  auto stage = [&](int tt, int bufb) {
    const char* kb = kpb + (size_t)tt * 16384;
    const char* vb = vpb + (size_t)tt * 128;
    char* lk = smc + bufb + w * 4096;
    char* lv = smc + bufb + 16384 + w * 4096;
#pragma unroll
    for (int i = 0; i < 4; ++i) {
      gld_lds16(kb + koff[i], lk + i * 1024);
      gld_lds16(vb + voff[i], lv + i * 1024);
    }
  };

  stage(0, 0);
  stage(1, 32768);

  for (int t = 0; t < NT; ++t) {
    asm volatile("s_waitcnt vmcnt(8)" ::: "memory");
    __builtin_amdgcn_s_barrier();
    const char* kb = smc + (t & 1) * 32768;
    const char* vb = kb + 16384;

    f32x16 s0, s1;
#pragma unroll
    for (int i = 0; i < 16; ++i) { s0[i] = 0.0f; s1[i] = 0.0f; }
    __builtin_amdgcn_s_setprio(1);
#pragma unroll
    for (int db = 0; db < 8; ++db) {
      const int q = 2 * db + h;
      bf16x8 k0 = *(const bf16x8*)(kb + l31 * 256 + (((q & 8) | ((q & 7) ^ sw0)) << 4));
      bf16x8 k1 = *(const bf16x8*)(kb + (32 + l31) * 256 + (((q & 8) | ((q & 7) ^ sw1)) << 4));
      s0 = mfma32(k0, qf[db], s0);
      s1 = mfma32(k1, qf[db], s1);
    }
    __builtin_amdgcn_s_setprio(0);

    float tmax = fmaxf(s0[0], s1[0]);
#pragma unroll
    for (int i = 1; i < 16; ++i) tmax = fmaxf(tmax, fmaxf(s0[i], s1[i]));
    tmax = fmaxf(tmax, __shfl_xor(tmax, 32));
    if (__any(tmax > m_run + 62.0f)) {
      float mnew = fmaxf(m_run, tmax);
      float fac = exp2f((m_run - mnew) * CEXP);
      m_run = mnew;
      lacc *= fac;
#pragma unroll
      for (int r = 0; r < 16; ++r) {
        float fr = __shfl(fac, (r & 3) + 8 * (r >> 2) + 4 * h);
#pragma unroll
        for (int nf = 0; nf < 4; ++nf) oacc[nf][r] *= fr;
      }
    }
    const float mc = m_run * CEXP;
#pragma unroll
    for (int i = 0; i < 16; ++i) s0[i] = exp2f(fmaf(s0[i], CEXP, -mc));
#pragma unroll
    for (int i = 0; i < 16; ++i) s1[i] = exp2f(fmaf(s1[i], CEXP, -mc));
    float a0 = 0.f, a1 = 0.f, a2 = 0.f, a3 = 0.f;
#pragma unroll
    for (int i = 0; i < 16; i += 4) {
      a0 += s0[i] + s1[i];         a1 += s0[i + 1] + s1[i + 1];
      a2 += s0[i + 2] + s1[i + 2]; a3 += s0[i + 3] + s1[i + 3];
    }
    lacc += (a0 + a1) + (a2 + a3);

    __builtin_amdgcn_s_setprio(1);
    {
      bf16x8 pf = build_pf<0>(s0, h);
#pragma unroll
      for (int nf = 0; nf < 4; ++nf) {
        bf16x8 vf = *(const bf16x8*)(vb + (nf * 32 + l31) * 128 + (((0 + h) ^ swv[nf]) << 4));
        oacc[nf] = mfma32(pf, vf, oacc[nf]);
      }
    }
    {
      bf16x8 pf = build_pf<8>(s0, h);
#pragma unroll
      for (int nf = 0; nf < 4; ++nf) {
        bf16x8 vf = *(const bf16x8*)(vb + (nf * 32 + l31) * 128 + (((2 + h) ^ swv[nf]) << 4));
        oacc[nf] = mfma32(pf, vf, oacc[nf]);
      }
    }
    {
      bf16x8 pf = build_pf<0>(s1, h);
#pragma unroll
      for (int nf = 0; nf < 4; ++nf) {
        bf16x8 vf = *(const bf16x8*)(vb + (nf * 32 + l31) * 128 + (((4 + h) ^ swv[nf]) << 4));
        oacc[nf] = mfma32(pf, vf, oacc[nf]);
      }
    }
    {
      bf16x8 pf = build_pf<8>(s1, h);
#pragma unroll
      for (int nf = 0; nf < 4; ++nf) {
        bf16x8 vf = *(const bf16x8*)(vb + (nf * 32 + l31) * 128 + (((6 + h) ^ swv[nf]) << 4));
        oacc[nf] = mfma32(pf, vf, oacc[nf]);
      }
    }
    __builtin_amdgcn_s_setprio(0);

    __builtin_amdgcn_s_barrier();
    stage((t + 2) & (NT - 1), (t & 1) * 32768);
  }
  asm volatile("s_waitcnt vmcnt(0)" ::: "memory");

  lacc += __shfl_xor(lacc, 32);
  if (SPLIT == 1) {
    const float inv = 1.0f / lacc;
    float* ob = out + (size_t)(b * 4096 + qbase) * 128;
#pragma unroll
    for (int r = 0; r < 16; ++r) {
      const int rowD = (r & 3) + 8 * (r >> 2) + 4 * h;
      float ir = __shfl(inv, rowD);
#pragma unroll
      for (int nf = 0; nf < 4; ++nf)
        ob[(size_t)rowD * 128 + nf * 32 + l31] = oacc[nf][r] * ir;
    }
  } else {
    const int pb = s * 256 + b * 32 + qt;
    if (lane < 32) {
      Mpart[pb * 128 + w * 32 + l31] = m_run;
      Lpart[pb * 128 + w * 32 + l31] = lacc;
    }
    float* ob = Opart + ((size_t)pb * 128 + w * 32) * 128;
#pragma unroll
    for (int r = 0; r < 16; ++r) {
      const int rowD = (r & 3) + 8 * (r >> 2) + 4 * h;
#pragma unroll
      for (int nf = 0; nf < 4; ++nf)
        ob[(size_t)rowD * 128 + nf * 32 + l31] = oacc[nf][r];
    }
  }
}

// Combine 2 split partials. grid 4096 x 256: 8 rows/block, 32 lanes/row (float4).
__global__ __launch_bounds__(256) void combine_kernel(
    const float* __restrict__ Opart, const float* __restrict__ Mpart,
    const float* __restrict__ Lpart, float* __restrict__ out) {
  const int g = blockIdx.x * 8 + (threadIdx.x >> 5);
  const int lane32 = threadIdx.x & 31;
  const int b = g >> 12;
  const int pos = g & 4095;
  const int qt = pos >> 7;
  const int row = pos & 127;
  const int i0 = (b * 32 + qt) * 128 + row;
  const int i1 = (256 + b * 32 + qt) * 128 + row;
  const float m0 = Mpart[i0], m1 = Mpart[i1];
  const float l0 = Lpart[i0], l1 = Lpart[i1];
  const float m = fmaxf(m0, m1);
  const float w0 = exp2f((m0 - m) * CEXP_CONST);
  const float w1 = exp2f((m1 - m) * CEXP_CONST);
  const float inv = 1.0f / (w0 * l0 + w1 * l1);
  const float4 o0 = *(const float4*)(Opart + (size_t)i0 * 128 + lane32 * 4);
  const float4 o1 = *(const float4*)(Opart + (size_t)i1 * 128 + lane32 * 4);
  float4 o;
  o.x = (w0 * o0.x + w1 * o1.x) * inv;
  o.y = (w0 * o0.y + w1 * o1.y) * inv;
  o.z = (w0 * o0.z + w1 * o1.z) * inv;
  o.w = (w0 * o0.w + w1 * o1.w) * inv;
  *(float4*)(out + (size_t)g * 128 + lane32 * 4) = o;
}

extern "C" void kernel_launch(void* const* d_in, const int* in_sizes, int n_in,
                              void* d_out, int out_size, void* d_ws, size_t ws_size,
                              hipStream_t stream) {
  const float* q  = (const float*)d_in[0];
  const float* k  = (const float*)d_in[1];
  const float* v  = (const float*)d_in[2];
  const float* Wq = (const float*)d_in[3];
  const float* Wk = (const float*)d_in[4];
  const float* Wv = (const float*)d_in[5];
  float* out = (float*)d_out;
  char* ws = (char*)d_ws;
  bf16_t* Wt2 = (bf16_t*)(ws);
  bf16_t* Qp = (bf16_t*)(ws + (size_t)(1u << 20));
  bf16_t* Kp = (bf16_t*)(ws + (size_t)(9u << 20));
  bf16_t* Vt = (bf16_t*)(ws + (size_t)(17u << 20));
  float* Opart = (float*)(ws + (size_t)(32u << 20));
  float* Mpart = (float*)(ws + (size_t)(64u << 20));
  float* Lpart = (float*)(ws + (size_t)(64u << 20) + (256u << 10));

  hipLaunchKernelGGL(wt_kernel, dim3(1536), dim3(256), 0, stream, Wq, Wk, Wv, Wt2);
  hipLaunchKernelGGL(proj_kernel, dim3(256, 3), dim3(256), 0, stream, q, k, v, Wt2, Qp, Kp, Vt);

  if (ws_size >= ((size_t)65 << 20)) {
    hipLaunchKernelGGL((attn_kernel<2>), dim3(512), dim3(256), 0, stream,
                       Qp, Kp, Vt, out, Opart, Mpart, Lpart);
    hipLaunchKernelGGL(combine_kernel, dim3(4096), dim3(256), 0, stream,
                       Opart, Mpart, Lpart, out);
  } else {
    hipLaunchKernelGGL((attn_kernel<1>), dim3(256), dim3(256), 0, stream,
                       Qp, Kp, Vt, out, Opart, Mpart, Lpart);
  }
}

// Round 10
// 213.986 us; speedup vs baseline: 1.2385x; 1.0288x over previous
//
#include <hip/hip_runtime.h>
#include <cstdint>
#include <cstddef>

typedef __bf16 bf16_t;
typedef __bf16 bf16x8 __attribute__((ext_vector_type(8)));
typedef __bf16 bf16x4v __attribute__((ext_vector_type(4)));
typedef float f32x16 __attribute__((ext_vector_type(16)));

static __device__ __forceinline__ f32x16 mfma32(bf16x8 a, bf16x8 b, f32x16 c) {
  return __builtin_amdgcn_mfma_f32_32x32x16_bf16(a, b, c, 0, 0, 0);
}

// Direct global->LDS DMA, 16B per lane (attn kernel only).
static __device__ __forceinline__ void gld_lds16(const void* g, void* l) {
  __builtin_amdgcn_global_load_lds(
      (const __attribute__((address_space(1))) unsigned int*)g,
      (__attribute__((address_space(3))) unsigned int*)l, 16, 0, 0);
}

#define CEXP_CONST 0.12754582f  // (1/sqrt(128)) * log2(e)

// ---------------------------------------------------------------------------
// Workspace layout (bytes):
//   [0, 768K)        Wt2   bf16 [3][64 k16][4 nf][2 h][32 l31][8]  (frag-major)
//   [1M, 9M)         Qp    bf16 [8][4096][128]
//   [9M, 17M)        Kp    bf16 [8][4096][128]
//   [17M, 25M)       Vt    bf16 [8][128][4096]
//   [32M, 64M)       Opart f32  [2*256][128][128]
//   [64M, +256K)     Mpart f32  [2*256*128]
//   [64M+256K,+256K) Lpart f32  [2*256*128]
// ---------------------------------------------------------------------------

// W -> fragment-major bf16: Wt2[((k16*4+nf)*2+h)*32+l31][j] = W[k16*16+h*8+j][nf*32+l31]
__global__ void wt_kernel(const float* __restrict__ Wq, const float* __restrict__ Wk,
                          const float* __restrict__ Wv, bf16_t* __restrict__ Wt2) {
  int t = blockIdx.x * 256 + threadIdx.x;   // 0..393215
  int tensor = t >> 17;
  int r = t & 131071;
  int j = r & 7, l31 = (r >> 3) & 31, h = (r >> 8) & 1, nf = (r >> 9) & 3, k16 = (r >> 11) & 63;
  int k = k16 * 16 + h * 8 + j, n = nf * 32 + l31;
  const float* W = tensor == 0 ? Wq : (tensor == 1 ? Wk : Wv);
  Wt2[t] = (bf16_t)W[(size_t)k * 128 + n];
}

// X[32768,1024]f32 @ W[1024,128] -> bf16.  BM=32, FULL-K LDS TILE:
// block's A footprint = one LINEAR 128KB span of X, read ONCE in ascending
// 16B chunks (memcpy pattern), converted f32->bf16 into swizzled LDS [32][1024].
// K-loop runs entirely from LDS; W read as 1KB-contiguous L2 fragments (Wt2).
// Wave w computes output columns nf=w (one 32x32 acc).
// ty: 0=Q, 1=K (row-major out), 2=V (transposed out).
__global__ __launch_bounds__(256, 2) void proj_kernel(
    const float* __restrict__ xq, const float* __restrict__ xk, const float* __restrict__ xv,
    const bf16_t* __restrict__ WtAll,
    bf16_t* __restrict__ Qp, bf16_t* __restrict__ Kp, bf16_t* __restrict__ Vt) {
  __shared__ __align__(16) char smc[65536];  // A-tile [32 rows][2048B], swizzled
  const int tid = threadIdx.x;
  const int ty = blockIdx.y;
  const int bm = blockIdx.x;               // 0..1023 (32-row blocks)
  const float* X = (ty == 0) ? xq : (ty == 1) ? xk : xv;
  const bf16_t* W2 = WtAll + (size_t)ty * 131072;
  const int lane = tid & 63;
  const int w = tid >> 6;
  const int l31 = lane & 31, h = lane >> 5;

  const char* aG = (const char*)X + (size_t)bm * 131072;  // linear 128KB span

  // chunk c (16B units, 0..8191): row = c>>8, slot = c&255 (within 4KB row).
  // LDS: bf16 row stride 2048B; 16B granule s16 = slot>>1, phys = s16 ^ (row&7).
  float4 gA[8], gB[8];
  auto ldg = [&](float4 (&buf)[8], int g) {
#pragma unroll
    for (int i = 0; i < 8; ++i)
      buf[i] = *(const float4*)(aG + (size_t)((g * 2048 + i * 256 + tid) << 4));
  };
  auto stg = [&](float4 (&buf)[8], int g) {
#pragma unroll
    for (int i = 0; i < 8; ++i) {
      int c = g * 2048 + i * 256 + tid;
      int row = c >> 8, slot = c & 255;
      bf16x4v bv;
      bv[0] = (bf16_t)buf[i].x; bv[1] = (bf16_t)buf[i].y;
      bv[2] = (bf16_t)buf[i].z; bv[3] = (bf16_t)buf[i].w;
      int dst = row * 2048 + (((slot >> 1) ^ (row & 7)) << 4) + (slot & 1) * 8;
      *(uint2*)(smc + dst) = __builtin_bit_cast(uint2, bv);
    }
  };

  ldg(gA, 0);
  ldg(gB, 1);
  stg(gA, 0);      // compiler waits only on gA regs; gB stays in flight
  ldg(gA, 2);
  stg(gB, 1);
  ldg(gB, 3);
  stg(gA, 2);
  stg(gB, 3);
  __syncthreads();

  // ---- K-loop: all A from LDS, W fragments from L2 (Wt2) ----
  f32x16 acc;
#pragma unroll
  for (int r = 0; r < 16; ++r) acc[r] = 0.0f;
  const bf16_t* wbase = W2 + w * 512 + lane * 8;
  const char* arow = smc + l31 * 2048;
  const int asw = l31 & 7;
#pragma unroll 16
  for (int k16 = 0; k16 < 64; ++k16) {
    bf16x8 af = *(const bf16x8*)(arow + ((((k16 << 1) | h) ^ asw) << 4));
    bf16x8 wf = *(const bf16x8*)(wbase + (size_t)k16 * 2048);
    acc = mfma32(af, wf, acc);
  }
  __syncthreads();   // all waves done reading A-tile; smc reused below

  // C/D map: col n = w*32 + l31, row m = (r&3) + 8*(r>>2) + 4*h.
  if (ty < 2) {
    // stage [32 m][264B], then 8KB coalesced out
    constexpr int RS = 264;
#pragma unroll
    for (int r = 0; r < 16; ++r) {
      int m = (r & 3) + 8 * (r >> 2) + 4 * h;
      *(bf16_t*)(smc + m * RS + (w * 32 + l31) * 2) = (bf16_t)acc[r];
    }
    __syncthreads();
    bf16_t* O = (ty == 0) ? Qp : Kp;
    char* obase = (char*)O + (size_t)bm * 8192;
#pragma unroll
    for (int i = 0; i < 2; ++i) {
      int c = i * 256 + tid;           // 512 x 16B chunks
      int rr = c >> 4, ch = c & 15;
      uint4 vv = *(const uint4*)(smc + rr * RS + ch * 16);
      *(uint4*)(obase + rr * 256 + ch * 16) = vv;
    }
  } else {
    // transpose: stage [128 n][72B pad], write Vt[b][n][m] in 32B chunks
#pragma unroll
    for (int q = 0; q < 4; ++q) {
      int n = w * 32 + l31;
      bf16x4v bv;
#pragma unroll
      for (int j = 0; j < 4; ++j) bv[j] = (bf16_t)acc[q * 4 + j];
      *(uint2*)(smc + n * 72 + q * 16 + h * 8) = __builtin_bit_cast(uint2, bv);
    }
    __syncthreads();
    const int bb = bm >> 7;            // batch
    const int m0 = (bm & 127) * 32;    // m offset within batch
    {
      int n = tid >> 1, half = tid & 1;
      const char* src = smc + n * 72 + half * 32;
      char* dst = (char*)Vt + (size_t)bb * 1048576 + (size_t)n * 8192 + m0 * 2 + half * 32;
      uint4 v0 = *(const uint4*)(src);
      uint4 v1 = *(const uint4*)(src + 16);
      *(uint4*)(dst) = v0;
      *(uint4*)(dst + 16) = v1;
    }
  }
}

// Build PV A-fragment in-register: 4x v_cvt_pk_bf16_f32 + 4x shfl_xor(32).
template <int B0>
static __device__ __forceinline__ bf16x8 build_pf(const f32x16& s, int h) {
  unsigned c0, c1, c2, c3;
  asm("v_cvt_pk_bf16_f32 %0, %1, %2" : "=v"(c0) : "v"(s[B0 + 0]), "v"(s[B0 + 1]));
  asm("v_cvt_pk_bf16_f32 %0, %1, %2" : "=v"(c1) : "v"(s[B0 + 2]), "v"(s[B0 + 3]));
  asm("v_cvt_pk_bf16_f32 %0, %1, %2" : "=v"(c2) : "v"(s[B0 + 4]), "v"(s[B0 + 5]));
  asm("v_cvt_pk_bf16_f32 %0, %1, %2" : "=v"(c3) : "v"(s[B0 + 6]), "v"(s[B0 + 7]));
  unsigned x0 = (unsigned)__shfl_xor((int)c0, 32);
  unsigned x1 = (unsigned)__shfl_xor((int)c1, 32);
  unsigned x2 = (unsigned)__shfl_xor((int)c2, 32);
  unsigned x3 = (unsigned)__shfl_xor((int)c3, 32);
  uint4 u;
  u.x = h ? x2 : c0;
  u.y = h ? x3 : c1;
  u.z = h ? c2 : x0;
  u.w = h ? c3 : x1;
  return __builtin_bit_cast(bf16x8, u);
}

// Flash attention (unchanged: gld_lds dbuf, counted vmcnt(8)).
template <int SPLIT>
__global__ __launch_bounds__(256, 2) void attn_kernel(
    const bf16_t* __restrict__ Qp, const bf16_t* __restrict__ Kp,
    const bf16_t* __restrict__ Vt, float* __restrict__ out,
    float* __restrict__ Opart, float* __restrict__ Mpart, float* __restrict__ Lpart) {
  __shared__ __align__(16) char smc[65536];  // 2 x (K 16K | V 16K)
  const int tid = threadIdx.x;
  const int lane = tid & 63, w = tid >> 6;
  const int l31 = lane & 31, h = lane >> 5;
  const int bid = blockIdx.x;
  const int b = bid & 7;
  const int qt = (bid >> 3) & 31;
  const int s = bid >> 8;
  const int NT = 64 / SPLIT;
  const float CEXP = CEXP_CONST;
  const int qbase = qt * 128 + w * 32;
  const int sw0 = (l31 ^ (l31 >> 3)) & 7;
  const int sw1 = sw0 ^ 4;

  bf16x8 qf[8];
  const bf16_t* qrow = Qp + (size_t)(b * 4096 + qbase + l31) * 128 + h * 8;
#pragma unroll
  for (int db = 0; db < 8; ++db) qf[db] = *(const bf16x8*)(qrow + db * 16);

  int swv[4];
#pragma unroll
  for (int nf = 0; nf < 4; ++nf) swv[nf] = (l31 & 7) ^ ((4 * nf + (l31 >> 3)) & 7);

  const int rl = lane >> 4, slK = lane & 15;
  const int dl = lane >> 3, slV = lane & 7;
  int koff[4], voff[4];
#pragma unroll
  for (int i = 0; i < 4; ++i) {
    int r = w * 16 + i * 4 + rl;
    int swr = (r ^ (r >> 3)) & 7;
    koff[i] = r * 256 + (((slK & 8) | ((slK & 7) ^ swr)) << 4);
    int d = w * 32 + i * 8 + dl;
    int swd = (d ^ (d >> 3)) & 7;
    voff[i] = d * 8192 + ((slV ^ swd) << 4);
  }
  const char* kpb = (const char*)Kp + (size_t)b * 1048576 + (size_t)s * NT * 16384;
  const char* vpb = (const char*)Vt + (size_t)b * 1048576 + (size_t)s * NT * 128;

  f32x16 oacc[4];
#pragma unroll
  for (int nf = 0; nf < 4; ++nf)
#pragma unroll
    for (int r = 0; r < 16; ++r) oacc[nf][r] = 0.0f;
  float m_run = -3.0e38f, lacc = 0.0f;

  auto stage = [&](int tt, int bufb) {
    const char* kb = kpb + (size_t)tt * 16384;
    const char* vb = vpb + (size_t)tt * 128;
    char* lk = smc + bufb + w * 4096;
    char* lv = smc + bufb + 16384 + w * 4096;
#pragma unroll
    for (int i = 0; i < 4; ++i) {
      gld_lds16(kb + koff[i], lk + i * 1024);
      gld_lds16(vb + voff[i], lv + i * 1024);
    }
  };

  stage(0, 0);
  stage(1, 32768);

  for (int t = 0; t < NT; ++t) {
    asm volatile("s_waitcnt vmcnt(8)" ::: "memory");
    __builtin_amdgcn_s_barrier();
    const char* kb = smc + (t & 1) * 32768;
    const char* vb = kb + 16384;

    f32x16 s0, s1;
#pragma unroll
    for (int i = 0; i < 16; ++i) { s0[i] = 0.0f; s1[i] = 0.0f; }
    __builtin_amdgcn_s_setprio(1);
#pragma unroll
    for (int db = 0; db < 8; ++db) {
      const int q = 2 * db + h;
      bf16x8 k0 = *(const bf16x8*)(kb + l31 * 256 + (((q & 8) | ((q & 7) ^ sw0)) << 4));
      bf16x8 k1 = *(const bf16x8*)(kb + (32 + l31) * 256 + (((q & 8) | ((q & 7) ^ sw1)) << 4));
      s0 = mfma32(k0, qf[db], s0);
      s1 = mfma32(k1, qf[db], s1);
    }
    __builtin_amdgcn_s_setprio(0);

    float tmax = fmaxf(s0[0], s1[0]);
#pragma unroll
    for (int i = 1; i < 16; ++i) tmax = fmaxf(tmax, fmaxf(s0[i], s1[i]));
    tmax = fmaxf(tmax, __shfl_xor(tmax, 32));
    if (__any(tmax > m_run + 62.0f)) {
      float mnew = fmaxf(m_run, tmax);
      float fac = exp2f((m_run - mnew) * CEXP);
      m_run = mnew;
      lacc *= fac;
#pragma unroll
      for (int r = 0; r < 16; ++r) {
        float fr = __shfl(fac, (r & 3) + 8 * (r >> 2) + 4 * h);
#pragma unroll
        for (int nf = 0; nf < 4; ++nf) oacc[nf][r] *= fr;
      }
    }
    const float mc = m_run * CEXP;
#pragma unroll
    for (int i = 0; i < 16; ++i) s0[i] = exp2f(fmaf(s0[i], CEXP, -mc));
#pragma unroll
    for (int i = 0; i < 16; ++i) s1[i] = exp2f(fmaf(s1[i], CEXP, -mc));
    float a0 = 0.f, a1 = 0.f, a2 = 0.f, a3 = 0.f;
#pragma unroll
    for (int i = 0; i < 16; i += 4) {
      a0 += s0[i] + s1[i];         a1 += s0[i + 1] + s1[i + 1];
      a2 += s0[i + 2] + s1[i + 2]; a3 += s0[i + 3] + s1[i + 3];
    }
    lacc += (a0 + a1) + (a2 + a3);

    __builtin_amdgcn_s_setprio(1);
    {
      bf16x8 pf = build_pf<0>(s0, h);
#pragma unroll
      for (int nf = 0; nf < 4; ++nf) {
        bf16x8 vf = *(const bf16x8*)(vb + (nf * 32 + l31) * 128 + (((0 + h) ^ swv[nf]) << 4));
        oacc[nf] = mfma32(pf, vf, oacc[nf]);
      }
    }
    {
      bf16x8 pf = build_pf<8>(s0, h);
#pragma unroll
      for (int nf = 0; nf < 4; ++nf) {
        bf16x8 vf = *(const bf16x8*)(vb + (nf * 32 + l31) * 128 + (((2 + h) ^ swv[nf]) << 4));
        oacc[nf] = mfma32(pf, vf, oacc[nf]);
      }
    }
    {
      bf16x8 pf = build_pf<0>(s1, h);
#pragma unroll
      for (int nf = 0; nf < 4; ++nf) {
        bf16x8 vf = *(const bf16x8*)(vb + (nf * 32 + l31) * 128 + (((4 + h) ^ swv[nf]) << 4));
        oacc[nf] = mfma32(pf, vf, oacc[nf]);
      }
    }
    {
      bf16x8 pf = build_pf<8>(s1, h);
#pragma unroll
      for (int nf = 0; nf < 4; ++nf) {
        bf16x8 vf = *(const bf16x8*)(vb + (nf * 32 + l31) * 128 + (((6 + h) ^ swv[nf]) << 4));
        oacc[nf] = mfma32(pf, vf, oacc[nf]);
      }
    }
    __builtin_amdgcn_s_setprio(0);

    __builtin_amdgcn_s_barrier();
    stage((t + 2) & (NT - 1), (t & 1) * 32768);
  }
  asm volatile("s_waitcnt vmcnt(0)" ::: "memory");

  lacc += __shfl_xor(lacc, 32);
  if (SPLIT == 1) {
    const float inv = 1.0f / lacc;
    float* ob = out + (size_t)(b * 4096 + qbase) * 128;
#pragma unroll
    for (int r = 0; r < 16; ++r) {
      const int rowD = (r & 3) + 8 * (r >> 2) + 4 * h;
      float ir = __shfl(inv, rowD);
#pragma unroll
      for (int nf = 0; nf < 4; ++nf)
        ob[(size_t)rowD * 128 + nf * 32 + l31] = oacc[nf][r] * ir;
    }
  } else {
    const int pb = s * 256 + b * 32 + qt;
    if (lane < 32) {
      Mpart[pb * 128 + w * 32 + l31] = m_run;
      Lpart[pb * 128 + w * 32 + l31] = lacc;
    }
    float* ob = Opart + ((size_t)pb * 128 + w * 32) * 128;
#pragma unroll
    for (int r = 0; r < 16; ++r) {
      const int rowD = (r & 3) + 8 * (r >> 2) + 4 * h;
#pragma unroll
      for (int nf = 0; nf < 4; ++nf)
        ob[(size_t)rowD * 128 + nf * 32 + l31] = oacc[nf][r];
    }
  }
}

// Combine 2 split partials. grid 4096 x 256: 8 rows/block, 32 lanes/row (float4).
__global__ __launch_bounds__(256) void combine_kernel(
    const float* __restrict__ Opart, const float* __restrict__ Mpart,
    const float* __restrict__ Lpart, float* __restrict__ out) {
  const int g = blockIdx.x * 8 + (threadIdx.x >> 5);
  const int lane32 = threadIdx.x & 31;
  const int b = g >> 12;
  const int pos = g & 4095;
  const int qt = pos >> 7;
  const int row = pos & 127;
  const int i0 = (b * 32 + qt) * 128 + row;
  const int i1 = (256 + b * 32 + qt) * 128 + row;
  const float m0 = Mpart[i0], m1 = Mpart[i1];
  const float l0 = Lpart[i0], l1 = Lpart[i1];
  const float m = fmaxf(m0, m1);
  const float w0 = exp2f((m0 - m) * CEXP_CONST);
  const float w1 = exp2f((m1 - m) * CEXP_CONST);
  const float inv = 1.0f / (w0 * l0 + w1 * l1);
  const float4 o0 = *(const float4*)(Opart + (size_t)i0 * 128 + lane32 * 4);
  const float4 o1 = *(const float4*)(Opart + (size_t)i1 * 128 + lane32 * 4);
  float4 o;
  o.x = (w0 * o0.x + w1 * o1.x) * inv;
  o.y = (w0 * o0.y + w1 * o1.y) * inv;
  o.z = (w0 * o0.z + w1 * o1.z) * inv;
  o.w = (w0 * o0.w + w1 * o1.w) * inv;
  *(float4*)(out + (size_t)g * 128 + lane32 * 4) = o;
}

extern "C" void kernel_launch(void* const* d_in, const int* in_sizes, int n_in,
                              void* d_out, int out_size, void* d_ws, size_t ws_size,
                              hipStream_t stream) {
  const float* q  = (const float*)d_in[0];
  const float* k  = (const float*)d_in[1];
  const float* v  = (const float*)d_in[2];
  const float* Wq = (const float*)d_in[3];
  const float* Wk = (const float*)d_in[4];
  const float* Wv = (const float*)d_in[5];
  float* out = (float*)d_out;
  char* ws = (char*)d_ws;
  bf16_t* Wt2 = (bf16_t*)(ws);
  bf16_t* Qp = (bf16_t*)(ws + (size_t)(1u << 20));
  bf16_t* Kp = (bf16_t*)(ws + (size_t)(9u << 20));
  bf16_t* Vt = (bf16_t*)(ws + (size_t)(17u << 20));
  float* Opart = (float*)(ws + (size_t)(32u << 20));
  float* Mpart = (float*)(ws + (size_t)(64u << 20));
  float* Lpart = (float*)(ws + (size_t)(64u << 20) + (256u << 10));

  hipLaunchKernelGGL(wt_kernel, dim3(1536), dim3(256), 0, stream, Wq, Wk, Wv, Wt2);
  hipLaunchKernelGGL(proj_kernel, dim3(1024, 3), dim3(256), 0, stream, q, k, v, Wt2, Qp, Kp, Vt);

  if (ws_size >= ((size_t)65 << 20)) {
    hipLaunchKernelGGL((attn_kernel<2>), dim3(512), dim3(256), 0, stream,
                       Qp, Kp, Vt, out, Opart, Mpart, Lpart);
    hipLaunchKernelGGL(combine_kernel, dim3(4096), dim3(256), 0, stream,
                       Opart, Mpart, Lpart, out);
  } else {
    hipLaunchKernelGGL((attn_kernel<1>), dim3(256), dim3(256), 0, stream,
                       Qp, Kp, Vt, out, Opart, Mpart, Lpart);
  }
}

// Round 11
// 209.867 us; speedup vs baseline: 1.2628x; 1.0196x over previous
//
#include <hip/hip_runtime.h>
#include <cstdint>
#include <cstddef>

typedef __bf16 bf16_t;
typedef __bf16 bf16x8 __attribute__((ext_vector_type(8)));
typedef __bf16 bf16x4v __attribute__((ext_vector_type(4)));
typedef float f32x16 __attribute__((ext_vector_type(16)));

static __device__ __forceinline__ f32x16 mfma32(bf16x8 a, bf16x8 b, f32x16 c) {
  return __builtin_amdgcn_mfma_f32_32x32x16_bf16(a, b, c, 0, 0, 0);
}

// Direct global->LDS DMA, 16B per lane (attn kernel only).
static __device__ __forceinline__ void gld_lds16(const void* g, void* l) {
  __builtin_amdgcn_global_load_lds(
      (const __attribute__((address_space(1))) unsigned int*)g,
      (__attribute__((address_space(3))) unsigned int*)l, 16, 0, 0);
}

#define CEXP_CONST 0.12754582f  // (1/sqrt(128)) * log2(e)

// ---------------------------------------------------------------------------
// Workspace layout (bytes):
//   [0, 768K)        Wt2   bf16 [3][64 k16][4 nf][2 h][32 l31][8]  (frag-major)
//   [1M, 9M)         Qp    bf16 [8][4096][128]
//   [9M, 17M)        Kp    bf16 [8][4096][128]
//   [17M, 25M)       Vt    bf16 [8][128][4096]
//   [32M, 64M)       Opart f32  [2*256][128][128]
//   [64M, +256K)     Mpart f32  [2*256*128]
//   [64M+256K,+256K) Lpart f32  [2*256*128]
// ---------------------------------------------------------------------------

// W -> fragment-major bf16: Wt2[((k16*4+nf)*2+h)*32+l31][j] = W[k16*16+h*8+j][nf*32+l31]
__global__ void wt_kernel(const float* __restrict__ Wq, const float* __restrict__ Wk,
                          const float* __restrict__ Wv, bf16_t* __restrict__ Wt2) {
  int t = blockIdx.x * 256 + threadIdx.x;   // 0..393215
  int tensor = t >> 17;
  int r = t & 131071;
  int j = r & 7, l31 = (r >> 3) & 31, h = (r >> 8) & 1, nf = (r >> 9) & 3, k16 = (r >> 11) & 63;
  int k = k16 * 16 + h * 8 + j, n = nf * 32 + l31;
  const float* W = tensor == 0 ? Wq : (tensor == 1 ? Wk : Wv);
  Wt2[t] = (bf16_t)W[(size_t)k * 128 + n];
}

// X[32768,1024]f32 @ W[1024,128] -> bf16.  BM=32, 8 K-phases, 4 blocks/CU.
// Concurrency experiment: 16 KB LDS (2 x 8KB A-phase buffers) -> 4 blocks/CU
// (16 waves, 2x R10); depth-2 register pipeline (named sets S0/S1) keeps each
// thread's phase-(p+2) loads in flight across two compute phases. W from
// fragment-major Wt2 (1KB contiguous L2 reads). Linear-ascending X reads.
// ty: 0=Q, 1=K (row-major out), 2=V (transposed out).
__global__ __launch_bounds__(256, 4) void proj_kernel(
    const float* __restrict__ xq, const float* __restrict__ xk, const float* __restrict__ xv,
    const bf16_t* __restrict__ WtAll,
    bf16_t* __restrict__ Qp, bf16_t* __restrict__ Kp, bf16_t* __restrict__ Vt) {
  __shared__ __align__(16) char smc[16384];  // 2 x 8KB A-buf; epilogue reuses
  const int tid = threadIdx.x;
  const int ty = blockIdx.y;
  const int bm = blockIdx.x;               // 0..1023 (32-row blocks)
  const float* X = (ty == 0) ? xq : (ty == 1) ? xk : xv;
  const bf16_t* W2 = WtAll + (size_t)ty * 131072;
  const int lane = tid & 63;
  const int w = tid >> 6;
  const int l31 = lane & 31, h = lane >> 5;

  const char* aG = (const char*)X + (size_t)bm * 131072;

  // Phase p covers k in [p*128, (p+1)*128). Stage: 1024 chunks of 16B f32;
  // chunk c: row = c>>5, slot s = c&31 (32 x 16B per row-phase).
  // LDS bf16 row stride 256B: dst granule (s>>1) ^ (row&7), half s&1.
  float4 S0[4], S1[4];
  auto ldg = [&](float4 (&S)[4], int p) {
#pragma unroll
    for (int i = 0; i < 4; ++i) {
      int c = i * 256 + tid;
      S[i] = *(const float4*)(aG + (size_t)(c >> 5) * 4096 + p * 512 + (c & 31) * 16);
    }
  };
  auto stg = [&](float4 (&S)[4], int buf) {
#pragma unroll
    for (int i = 0; i < 4; ++i) {
      int c = i * 256 + tid;
      int row = c >> 5, s = c & 31;
      bf16x4v bv;
      bv[0] = (bf16_t)S[i].x; bv[1] = (bf16_t)S[i].y;
      bv[2] = (bf16_t)S[i].z; bv[3] = (bf16_t)S[i].w;
      int dst = buf * 8192 + row * 256 + ((((s >> 1) ^ (row & 7)) << 4)) + (s & 1) * 8;
      *(uint2*)(smc + dst) = __builtin_bit_cast(uint2, bv);
    }
  };

  f32x16 acc;
#pragma unroll
  for (int r = 0; r < 16; ++r) acc[r] = 0.0f;
  const bf16_t* wbase = W2 + w * 512 + lane * 8;
  const int asw = l31 & 7;
  const char* arow0 = smc + l31 * 256;

  auto kloop = [&](int p) {
    const char* arow = arow0 + (p & 1) * 8192;
    const bf16_t* wp = wbase + (size_t)(p * 8) * 2048;
#pragma unroll
    for (int kk = 0; kk < 8; ++kk) {
      bf16x8 af = *(const bf16x8*)(arow + (((kk * 2 + h) ^ asw) << 4));
      bf16x8 wf = *(const bf16x8*)(wp + (size_t)kk * 2048);
      acc = mfma32(af, wf, acc);
    }
  };

  // prologue: S0=d(0), S1=d(1); buf0<-d(0); S0=d(2)
  ldg(S0, 0);
  ldg(S1, 1);
  stg(S0, 0);
  ldg(S0, 2);
  __syncthreads();

#pragma unroll
  for (int p2 = 0; p2 < 4; ++p2) {
    {
      const int p = 2 * p2;
      kloop(p);
      __builtin_amdgcn_s_barrier();
      stg(S1, 1);                    // d(p+1) -> buf1 (loads issued 2 phases ago)
      if (p + 3 < 8) ldg(S1, p + 3);
      asm volatile("s_waitcnt lgkmcnt(0)" ::: "memory");
      __builtin_amdgcn_s_barrier();
    }
    {
      const int p = 2 * p2 + 1;
      kloop(p);
      __builtin_amdgcn_s_barrier();
      if (p < 7) {
        stg(S0, 0);                  // d(p+1) -> buf0
        if (p + 3 < 8) ldg(S0, p + 3);
        asm volatile("s_waitcnt lgkmcnt(0)" ::: "memory");
      }
      __builtin_amdgcn_s_barrier();
    }
  }
  __syncthreads();   // all waves done; smc reused below

  // C/D map: col n = w*32 + l31, row m = (r&3) + 8*(r>>2) + 4*h.
  if (ty < 2) {
    constexpr int RS = 264;
#pragma unroll
    for (int r = 0; r < 16; ++r) {
      int m = (r & 3) + 8 * (r >> 2) + 4 * h;
      *(bf16_t*)(smc + m * RS + (w * 32 + l31) * 2) = (bf16_t)acc[r];
    }
    __syncthreads();
    bf16_t* O = (ty == 0) ? Qp : Kp;
    char* obase = (char*)O + (size_t)bm * 8192;
#pragma unroll
    for (int i = 0; i < 2; ++i) {
      int c = i * 256 + tid;           // 512 x 16B chunks
      int rr = c >> 4, ch = c & 15;
      uint4 vv = *(const uint4*)(smc + rr * RS + ch * 16);
      *(uint4*)(obase + rr * 256 + ch * 16) = vv;
    }
  } else {
    // transpose: stage [128 n][72B pad], write Vt[b][n][m] in 32B chunks
#pragma unroll
    for (int q = 0; q < 4; ++q) {
      int n = w * 32 + l31;
      bf16x4v bv;
#pragma unroll
      for (int j = 0; j < 4; ++j) bv[j] = (bf16_t)acc[q * 4 + j];
      *(uint2*)(smc + n * 72 + q * 16 + h * 8) = __builtin_bit_cast(uint2, bv);
    }
    __syncthreads();
    const int bb = bm >> 7;            // batch
    const int m0 = (bm & 127) * 32;    // m offset within batch
    {
      int n = tid >> 1, half = tid & 1;
      const char* src = smc + n * 72 + half * 32;
      char* dst = (char*)Vt + (size_t)bb * 1048576 + (size_t)n * 8192 + m0 * 2 + half * 32;
      uint4 v0 = *(const uint4*)(src);
      uint4 v1 = *(const uint4*)(src + 16);
      *(uint4*)(dst) = v0;
      *(uint4*)(dst + 16) = v1;
    }
  }
}

// Build PV A-fragment in-register: 4x v_cvt_pk_bf16_f32 + 4x shfl_xor(32).
template <int B0>
static __device__ __forceinline__ bf16x8 build_pf(const f32x16& s, int h) {
  unsigned c0, c1, c2, c3;
  asm("v_cvt_pk_bf16_f32 %0, %1, %2" : "=v"(c0) : "v"(s[B0 + 0]), "v"(s[B0 + 1]));
  asm("v_cvt_pk_bf16_f32 %0, %1, %2" : "=v"(c1) : "v"(s[B0 + 2]), "v"(s[B0 + 3]));
  asm("v_cvt_pk_bf16_f32 %0, %1, %2" : "=v"(c2) : "v"(s[B0 + 4]), "v"(s[B0 + 5]));
  asm("v_cvt_pk_bf16_f32 %0, %1, %2" : "=v"(c3) : "v"(s[B0 + 6]), "v"(s[B0 + 7]));
  unsigned x0 = (unsigned)__shfl_xor((int)c0, 32);
  unsigned x1 = (unsigned)__shfl_xor((int)c1, 32);
  unsigned x2 = (unsigned)__shfl_xor((int)c2, 32);
  unsigned x3 = (unsigned)__shfl_xor((int)c3, 32);
  uint4 u;
  u.x = h ? x2 : c0;
  u.y = h ? x3 : c1;
  u.z = h ? c2 : x0;
  u.w = h ? c3 : x1;
  return __builtin_bit_cast(bf16x8, u);
}

// Flash attention (unchanged: gld_lds dbuf, counted vmcnt(8)).
template <int SPLIT>
__global__ __launch_bounds__(256, 2) void attn_kernel(
    const bf16_t* __restrict__ Qp, const bf16_t* __restrict__ Kp,
    const bf16_t* __restrict__ Vt, float* __restrict__ out,
    float* __restrict__ Opart, float* __restrict__ Mpart, float* __restrict__ Lpart) {
  __shared__ __align__(16) char smc[65536];  // 2 x (K 16K | V 16K)
  const int tid = threadIdx.x;
  const int lane = tid & 63, w = tid >> 6;
  const int l31 = lane & 31, h = lane >> 5;
  const int bid = blockIdx.x;
  const int b = bid & 7;
  const int qt = (bid >> 3) & 31;
  const int s = bid >> 8;
  const int NT = 64 / SPLIT;
  const float CEXP = CEXP_CONST;
  const int qbase = qt * 128 + w * 32;
  const int sw0 = (l31 ^ (l31 >> 3)) & 7;
  const int sw1 = sw0 ^ 4;

  bf16x8 qf[8];
  const bf16_t* qrow = Qp + (size_t)(b * 4096 + qbase + l31) * 128 + h * 8;
#pragma unroll
  for (int db = 0; db < 8; ++db) qf[db] = *(const bf16x8*)(qrow + db * 16);

  int swv[4];
#pragma unroll
  for (int nf = 0; nf < 4; ++nf) swv[nf] = (l31 & 7) ^ ((4 * nf + (l31 >> 3)) & 7);

  const int rl = lane >> 4, slK = lane & 15;
  const int dl = lane >> 3, slV = lane & 7;
  int koff[4], voff[4];
#pragma unroll
  for (int i = 0; i < 4; ++i) {
    int r = w * 16 + i * 4 + rl;
    int swr = (r ^ (r >> 3)) & 7;
    koff[i] = r * 256 + (((slK & 8) | ((slK & 7) ^ swr)) << 4);
    int d = w * 32 + i * 8 + dl;
    int swd = (d ^ (d >> 3)) & 7;
    voff[i] = d * 8192 + ((slV ^ swd) << 4);
  }
  const char* kpb = (const char*)Kp + (size_t)b * 1048576 + (size_t)s * NT * 16384;
  const char* vpb = (const char*)Vt + (size_t)b * 1048576 + (size_t)s * NT * 128;

  f32x16 oacc[4];
#pragma unroll
  for (int nf = 0; nf < 4; ++nf)
#pragma unroll
    for (int r = 0; r < 16; ++r) oacc[nf][r] = 0.0f;
  float m_run = -3.0e38f, lacc = 0.0f;

  auto stage = [&](int tt, int bufb) {
    const char* kb = kpb + (size_t)tt * 16384;
    const char* vb = vpb + (size_t)tt * 128;
    char* lk = smc + bufb + w * 4096;
    char* lv = smc + bufb + 16384 + w * 4096;
#pragma unroll
    for (int i = 0; i < 4; ++i) {
      gld_lds16(kb + koff[i], lk + i * 1024);
      gld_lds16(vb + voff[i], lv + i * 1024);
    }
  };

  stage(0, 0);
  stage(1, 32768);

  for (int t = 0; t < NT; ++t) {
    asm volatile("s_waitcnt vmcnt(8)" ::: "memory");
    __builtin_amdgcn_s_barrier();
    const char* kb = smc + (t & 1) * 32768;
    const char* vb = kb + 16384;

    f32x16 s0, s1;
#pragma unroll
    for (int i = 0; i < 16; ++i) { s0[i] = 0.0f; s1[i] = 0.0f; }
    __builtin_amdgcn_s_setprio(1);
#pragma unroll
    for (int db = 0; db < 8; ++db) {
      const int q = 2 * db + h;
      bf16x8 k0 = *(const bf16x8*)(kb + l31 * 256 + (((q & 8) | ((q & 7) ^ sw0)) << 4));
      bf16x8 k1 = *(const bf16x8*)(kb + (32 + l31) * 256 + (((q & 8) | ((q & 7) ^ sw1)) << 4));
      s0 = mfma32(k0, qf[db], s0);
      s1 = mfma32(k1, qf[db], s1);
    }
    __builtin_amdgcn_s_setprio(0);

    float tmax = fmaxf(s0[0], s1[0]);
#pragma unroll
    for (int i = 1; i < 16; ++i) tmax = fmaxf(tmax, fmaxf(s0[i], s1[i]));
    tmax = fmaxf(tmax, __shfl_xor(tmax, 32));
    if (__any(tmax > m_run + 62.0f)) {
      float mnew = fmaxf(m_run, tmax);
      float fac = exp2f((m_run - mnew) * CEXP);
      m_run = mnew;
      lacc *= fac;
#pragma unroll
      for (int r = 0; r < 16; ++r) {
        float fr = __shfl(fac, (r & 3) + 8 * (r >> 2) + 4 * h);
#pragma unroll
        for (int nf = 0; nf < 4; ++nf) oacc[nf][r] *= fr;
      }
    }
    const float mc = m_run * CEXP;
#pragma unroll
    for (int i = 0; i < 16; ++i) s0[i] = exp2f(fmaf(s0[i], CEXP, -mc));
#pragma unroll
    for (int i = 0; i < 16; ++i) s1[i] = exp2f(fmaf(s1[i], CEXP, -mc));
    float a0 = 0.f, a1 = 0.f, a2 = 0.f, a3 = 0.f;
#pragma unroll
    for (int i = 0; i < 16; i += 4) {
      a0 += s0[i] + s1[i];         a1 += s0[i + 1] + s1[i + 1];
      a2 += s0[i + 2] + s1[i + 2]; a3 += s0[i + 3] + s1[i + 3];
    }
    lacc += (a0 + a1) + (a2 + a3);

    __builtin_amdgcn_s_setprio(1);
    {
      bf16x8 pf = build_pf<0>(s0, h);
#pragma unroll
      for (int nf = 0; nf < 4; ++nf) {
        bf16x8 vf = *(const bf16x8*)(vb + (nf * 32 + l31) * 128 + (((0 + h) ^ swv[nf]) << 4));
        oacc[nf] = mfma32(pf, vf, oacc[nf]);
      }
    }
    {
      bf16x8 pf = build_pf<8>(s0, h);
#pragma unroll
      for (int nf = 0; nf < 4; ++nf) {
        bf16x8 vf = *(const bf16x8*)(vb + (nf * 32 + l31) * 128 + (((2 + h) ^ swv[nf]) << 4));
        oacc[nf] = mfma32(pf, vf, oacc[nf]);
      }
    }
    {
      bf16x8 pf = build_pf<0>(s1, h);
#pragma unroll
      for (int nf = 0; nf < 4; ++nf) {
        bf16x8 vf = *(const bf16x8*)(vb + (nf * 32 + l31) * 128 + (((4 + h) ^ swv[nf]) << 4));
        oacc[nf] = mfma32(pf, vf, oacc[nf]);
      }
    }
    {
      bf16x8 pf = build_pf<8>(s1, h);
#pragma unroll
      for (int nf = 0; nf < 4; ++nf) {
        bf16x8 vf = *(const bf16x8*)(vb + (nf * 32 + l31) * 128 + (((6 + h) ^ swv[nf]) << 4));
        oacc[nf] = mfma32(pf, vf, oacc[nf]);
      }
    }
    __builtin_amdgcn_s_setprio(0);

    __builtin_amdgcn_s_barrier();
    stage((t + 2) & (NT - 1), (t & 1) * 32768);
  }
  asm volatile("s_waitcnt vmcnt(0)" ::: "memory");

  lacc += __shfl_xor(lacc, 32);
  if (SPLIT == 1) {
    const float inv = 1.0f / lacc;
    float* ob = out + (size_t)(b * 4096 + qbase) * 128;
#pragma unroll
    for (int r = 0; r < 16; ++r) {
      const int rowD = (r & 3) + 8 * (r >> 2) + 4 * h;
      float ir = __shfl(inv, rowD);
#pragma unroll
      for (int nf = 0; nf < 4; ++nf)
        ob[(size_t)rowD * 128 + nf * 32 + l31] = oacc[nf][r] * ir;
    }
  } else {
    const int pb = s * 256 + b * 32 + qt;
    if (lane < 32) {
      Mpart[pb * 128 + w * 32 + l31] = m_run;
      Lpart[pb * 128 + w * 32 + l31] = lacc;
    }
    float* ob = Opart + ((size_t)pb * 128 + w * 32) * 128;
#pragma unroll
    for (int r = 0; r < 16; ++r) {
      const int rowD = (r & 3) + 8 * (r >> 2) + 4 * h;
#pragma unroll
      for (int nf = 0; nf < 4; ++nf)
        ob[(size_t)rowD * 128 + nf * 32 + l31] = oacc[nf][r];
    }
  }
}

// Combine 2 split partials. grid 4096 x 256: 8 rows/block, 32 lanes/row (float4).
__global__ __launch_bounds__(256) void combine_kernel(
    const float* __restrict__ Opart, const float* __restrict__ Mpart,
    const float* __restrict__ Lpart, float* __restrict__ out) {
  const int g = blockIdx.x * 8 + (threadIdx.x >> 5);
  const int lane32 = threadIdx.x & 31;
  const int b = g >> 12;
  const int pos = g & 4095;
  const int qt = pos >> 7;
  const int row = pos & 127;
  const int i0 = (b * 32 + qt) * 128 + row;
  const int i1 = (256 + b * 32 + qt) * 128 + row;
  const float m0 = Mpart[i0], m1 = Mpart[i1];
  const float l0 = Lpart[i0], l1 = Lpart[i1];
  const float m = fmaxf(m0, m1);
  const float w0 = exp2f((m0 - m) * CEXP_CONST);
  const float w1 = exp2f((m1 - m) * CEXP_CONST);
  const float inv = 1.0f / (w0 * l0 + w1 * l1);
  const float4 o0 = *(const float4*)(Opart + (size_t)i0 * 128 + lane32 * 4);
  const float4 o1 = *(const float4*)(Opart + (size_t)i1 * 128 + lane32 * 4);
  float4 o;
  o.x = (w0 * o0.x + w1 * o1.x) * inv;
  o.y = (w0 * o0.y + w1 * o1.y) * inv;
  o.z = (w0 * o0.z + w1 * o1.z) * inv;
  o.w = (w0 * o0.w + w1 * o1.w) * inv;
  *(float4*)(out + (size_t)g * 128 + lane32 * 4) = o;
}

extern "C" void kernel_launch(void* const* d_in, const int* in_sizes, int n_in,
                              void* d_out, int out_size, void* d_ws, size_t ws_size,
                              hipStream_t stream) {
  const float* q  = (const float*)d_in[0];
  const float* k  = (const float*)d_in[1];
  const float* v  = (const float*)d_in[2];
  const float* Wq = (const float*)d_in[3];
  const float* Wk = (const float*)d_in[4];
  const float* Wv = (const float*)d_in[5];
  float* out = (float*)d_out;
  char* ws = (char*)d_ws;
  bf16_t* Wt2 = (bf16_t*)(ws);
  bf16_t* Qp = (bf16_t*)(ws + (size_t)(1u << 20));
  bf16_t* Kp = (bf16_t*)(ws + (size_t)(9u << 20));
  bf16_t* Vt = (bf16_t*)(ws + (size_t)(17u << 20));
  float* Opart = (float*)(ws + (size_t)(32u << 20));
  float* Mpart = (float*)(ws + (size_t)(64u << 20));
  float* Lpart = (float*)(ws + (size_t)(64u << 20) + (256u << 10));

  hipLaunchKernelGGL(wt_kernel, dim3(1536), dim3(256), 0, stream, Wq, Wk, Wv, Wt2);
  hipLaunchKernelGGL(proj_kernel, dim3(1024, 3), dim3(256), 0, stream, q, k, v, Wt2, Qp, Kp, Vt);

  if (ws_size >= ((size_t)65 << 20)) {
    hipLaunchKernelGGL((attn_kernel<2>), dim3(512), dim3(256), 0, stream,
                       Qp, Kp, Vt, out, Opart, Mpart, Lpart);
    hipLaunchKernelGGL(combine_kernel, dim3(4096), dim3(256), 0, stream,
                       Opart, Mpart, Lpart, out);
  } else {
    hipLaunchKernelGGL((attn_kernel<1>), dim3(256), dim3(256), 0, stream,
                       Qp, Kp, Vt, out, Opart, Mpart, Lpart);
  }
}

// Round 12
// 206.345 us; speedup vs baseline: 1.2844x; 1.0171x over previous
//
#include <hip/hip_runtime.h>
#include <cstdint>
#include <cstddef>

typedef __bf16 bf16_t;
typedef __bf16 bf16x8 __attribute__((ext_vector_type(8)));
typedef __bf16 bf16x4v __attribute__((ext_vector_type(4)));
typedef float f32x16 __attribute__((ext_vector_type(16)));

static __device__ __forceinline__ f32x16 mfma32(bf16x8 a, bf16x8 b, f32x16 c) {
  return __builtin_amdgcn_mfma_f32_32x32x16_bf16(a, b, c, 0, 0, 0);
}

// Direct global->LDS DMA, 16B per lane (attn kernel only).
static __device__ __forceinline__ void gld_lds16(const void* g, void* l) {
  __builtin_amdgcn_global_load_lds(
      (const __attribute__((address_space(1))) unsigned int*)g,
      (__attribute__((address_space(3))) unsigned int*)l, 16, 0, 0);
}

#define CEXP_CONST 0.12754582f  // (1/sqrt(128)) * log2(e)

// ---------------------------------------------------------------------------
// Workspace layout (bytes):
//   [0, 768K)        Wt2   bf16 [3][64 k16][4 nf][2 h][32 l31][8]  (frag-major)
//   [1M, 9M)         Qp    bf16 [8][4096][128]
//   [9M, 17M)        Kp    bf16 [8][4096][128]
//   [17M, 25M)       Vt    bf16 [8][128][4096]
//   [32M, 64M)       Opart f32  [2*256][128][128]
//   [64M, +256K)     Mpart f32  [2*256*128]
//   [64M+256K,+256K) Lpart f32  [2*256*128]
// ---------------------------------------------------------------------------

// W -> fragment-major bf16: Wt2[((k16*4+nf)*2+h)*32+l31][j] = W[k16*16+h*8+j][nf*32+l31]
__global__ void wt_kernel(const float* __restrict__ Wq, const float* __restrict__ Wk,
                          const float* __restrict__ Wv, bf16_t* __restrict__ Wt2) {
  int t = blockIdx.x * 256 + threadIdx.x;   // 0..393215
  int tensor = t >> 17;
  int r = t & 131071;
  int j = r & 7, l31 = (r >> 3) & 31, h = (r >> 8) & 1, nf = (r >> 9) & 3, k16 = (r >> 11) & 63;
  int k = k16 * 16 + h * 8 + j, n = nf * 32 + l31;
  const float* W = tensor == 0 ? Wq : (tensor == 1 ? Wk : Wv);
  Wt2[t] = (bf16_t)W[(size_t)k * 128 + n];
}

// X[32768,1024]f32 @ W[1024,128] -> bf16.  BM=32, 8 K-phases, 4 blocks/CU.
// R12: W(p+1) REGISTER-PREFETCHED (wA/wB alternation, static indexing) so the
// per-phase L2 W-load latency is off the MFMA critical path; ONE barrier per
// phase (double-buffered A-LDS makes the pre-write barrier redundant).
// X staged via single S[4] register set, linear-ascending reads.
// ty: 0=Q, 1=K (row-major out), 2=V (transposed out).
__global__ __launch_bounds__(256, 4) void proj_kernel(
    const float* __restrict__ xq, const float* __restrict__ xk, const float* __restrict__ xv,
    const bf16_t* __restrict__ WtAll,
    bf16_t* __restrict__ Qp, bf16_t* __restrict__ Kp, bf16_t* __restrict__ Vt) {
  __shared__ __align__(16) char smc[16384];  // 2 x 8KB A-buf; epilogue reuses
  const int tid = threadIdx.x;
  const int ty = blockIdx.y;
  const int bm = blockIdx.x;               // 0..1023 (32-row blocks)
  const float* X = (ty == 0) ? xq : (ty == 1) ? xk : xv;
  const bf16_t* W2 = WtAll + (size_t)ty * 131072;
  const int lane = tid & 63;
  const int w = tid >> 6;
  const int l31 = lane & 31, h = lane >> 5;

  const char* aG = (const char*)X + (size_t)bm * 131072;

  // Phase p covers k in [p*128, (p+1)*128). 512 chunks of 16B f32;
  // chunk c: row = c>>5, slot s = c&31. LDS bf16 row stride 256B:
  // dst granule (s>>1) ^ (row&7), half s&1.
  float4 S[4];
  auto ldg = [&](int p) {
#pragma unroll
    for (int i = 0; i < 4; ++i) {
      int c = i * 256 + tid;
      S[i] = *(const float4*)(aG + (size_t)(c >> 5) * 4096 + p * 512 + (c & 31) * 16);
    }
  };
  auto stg = [&](int buf) {
#pragma unroll
    for (int i = 0; i < 4; ++i) {
      int c = i * 256 + tid;
      int row = c >> 5, s = c & 31;
      bf16x4v bv;
      bv[0] = (bf16_t)S[i].x; bv[1] = (bf16_t)S[i].y;
      bv[2] = (bf16_t)S[i].z; bv[3] = (bf16_t)S[i].w;
      int dst = buf * 8192 + row * 256 + ((((s >> 1) ^ (row & 7)) << 4)) + (s & 1) * 8;
      *(uint2*)(smc + dst) = __builtin_bit_cast(uint2, bv);
    }
  };

  bf16x8 wA[8], wB[8];
  const bf16_t* wbase = W2 + w * 512 + lane * 8;
  auto ldw = [&](bf16x8 (&Wf)[8], int p) {
#pragma unroll
    for (int kk = 0; kk < 8; ++kk)
      Wf[kk] = *(const bf16x8*)(wbase + (size_t)(p * 8 + kk) * 2048);
  };

  f32x16 acc;
#pragma unroll
  for (int r = 0; r < 16; ++r) acc[r] = 0.0f;
  const int asw = l31 & 7;
  auto kloop = [&](bf16x8 (&Wf)[8], int buf) {
    const char* arow = smc + buf * 8192 + l31 * 256;
#pragma unroll
    for (int kk = 0; kk < 8; ++kk) {
      bf16x8 af = *(const bf16x8*)(arow + (((kk * 2 + h) ^ asw) << 4));
      acc = mfma32(af, Wf[kk], acc);
    }
  };

  // prologue: data(0) -> buf0; S <- data(1); wA <- W(0)
  ldg(0);
  stg(0);
  ldg(1);
  ldw(wA, 0);
  __syncthreads();

#pragma unroll
  for (int p2 = 0; p2 < 4; ++p2) {
    const int pe = 2 * p2;
    // even phase pe: compute with wA (buf pe&1=0), prefetch wB <- W(pe+1)
    ldw(wB, pe + 1);
    kloop(wA, 0);
    stg(1);                       // data(pe+1) -> buf1 (nobody reads buf1 now)
    if (pe + 2 < 8) ldg(pe + 2);  // issue X two phases ahead
    __syncthreads();
    // odd phase po = pe+1: compute with wB (buf1), prefetch wA <- W(po+1)
    const int po = pe + 1;
    if (po + 1 < 8) ldw(wA, po + 1);
    kloop(wB, 1);
    if (po + 1 < 8) {
      stg(0);                     // data(po+1) -> buf0
      if (po + 2 < 8) ldg(po + 2);
    }
    __syncthreads();
  }
  // smc reused below (last barrier above protects it)

  // C/D map: col n = w*32 + l31, row m = (r&3) + 8*(r>>2) + 4*h.
  if (ty < 2) {
    constexpr int RS = 264;
#pragma unroll
    for (int r = 0; r < 16; ++r) {
      int m = (r & 3) + 8 * (r >> 2) + 4 * h;
      *(bf16_t*)(smc + m * RS + (w * 32 + l31) * 2) = (bf16_t)acc[r];
    }
    __syncthreads();
    bf16_t* O = (ty == 0) ? Qp : Kp;
    char* obase = (char*)O + (size_t)bm * 8192;
#pragma unroll
    for (int i = 0; i < 2; ++i) {
      int c = i * 256 + tid;           // 512 x 16B chunks
      int rr = c >> 4, ch = c & 15;
      uint4 vv = *(const uint4*)(smc + rr * RS + ch * 16);
      *(uint4*)(obase + rr * 256 + ch * 16) = vv;
    }
  } else {
    // transpose: stage [128 n][72B pad], write Vt[b][n][m] in 32B chunks
#pragma unroll
    for (int q = 0; q < 4; ++q) {
      int n = w * 32 + l31;
      bf16x4v bv;
#pragma unroll
      for (int j = 0; j < 4; ++j) bv[j] = (bf16_t)acc[q * 4 + j];
      *(uint2*)(smc + n * 72 + q * 16 + h * 8) = __builtin_bit_cast(uint2, bv);
    }
    __syncthreads();
    const int bb = bm >> 7;            // batch
    const int m0 = (bm & 127) * 32;    // m offset within batch
    {
      int n = tid >> 1, half = tid & 1;
      const char* src = smc + n * 72 + half * 32;
      char* dst = (char*)Vt + (size_t)bb * 1048576 + (size_t)n * 8192 + m0 * 2 + half * 32;
      uint4 v0 = *(const uint4*)(src);
      uint4 v1 = *(const uint4*)(src + 16);
      *(uint4*)(dst) = v0;
      *(uint4*)(dst + 16) = v1;
    }
  }
}

// Build PV A-fragment in-register: 4x v_cvt_pk_bf16_f32 + 4x shfl_xor(32).
template <int B0>
static __device__ __forceinline__ bf16x8 build_pf(const f32x16& s, int h) {
  unsigned c0, c1, c2, c3;
  asm("v_cvt_pk_bf16_f32 %0, %1, %2" : "=v"(c0) : "v"(s[B0 + 0]), "v"(s[B0 + 1]));
  asm("v_cvt_pk_bf16_f32 %0, %1, %2" : "=v"(c1) : "v"(s[B0 + 2]), "v"(s[B0 + 3]));
  asm("v_cvt_pk_bf16_f32 %0, %1, %2" : "=v"(c2) : "v"(s[B0 + 4]), "v"(s[B0 + 5]));
  asm("v_cvt_pk_bf16_f32 %0, %1, %2" : "=v"(c3) : "v"(s[B0 + 6]), "v"(s[B0 + 7]));
  unsigned x0 = (unsigned)__shfl_xor((int)c0, 32);
  unsigned x1 = (unsigned)__shfl_xor((int)c1, 32);
  unsigned x2 = (unsigned)__shfl_xor((int)c2, 32);
  unsigned x3 = (unsigned)__shfl_xor((int)c3, 32);
  uint4 u;
  u.x = h ? x2 : c0;
  u.y = h ? x3 : c1;
  u.z = h ? c2 : x0;
  u.w = h ? c3 : x1;
  return __builtin_bit_cast(bf16x8, u);
}

// Flash attention (unchanged: gld_lds dbuf, counted vmcnt(8)).
template <int SPLIT>
__global__ __launch_bounds__(256, 2) void attn_kernel(
    const bf16_t* __restrict__ Qp, const bf16_t* __restrict__ Kp,
    const bf16_t* __restrict__ Vt, float* __restrict__ out,
    float* __restrict__ Opart, float* __restrict__ Mpart, float* __restrict__ Lpart) {
  __shared__ __align__(16) char smc[65536];  // 2 x (K 16K | V 16K)
  const int tid = threadIdx.x;
  const int lane = tid & 63, w = tid >> 6;
  const int l31 = lane & 31, h = lane >> 5;
  const int bid = blockIdx.x;
  const int b = bid & 7;
  const int qt = (bid >> 3) & 31;
  const int s = bid >> 8;
  const int NT = 64 / SPLIT;
  const float CEXP = CEXP_CONST;
  const int qbase = qt * 128 + w * 32;
  const int sw0 = (l31 ^ (l31 >> 3)) & 7;
  const int sw1 = sw0 ^ 4;

  bf16x8 qf[8];
  const bf16_t* qrow = Qp + (size_t)(b * 4096 + qbase + l31) * 128 + h * 8;
#pragma unroll
  for (int db = 0; db < 8; ++db) qf[db] = *(const bf16x8*)(qrow + db * 16);

  int swv[4];
#pragma unroll
  for (int nf = 0; nf < 4; ++nf) swv[nf] = (l31 & 7) ^ ((4 * nf + (l31 >> 3)) & 7);

  const int rl = lane >> 4, slK = lane & 15;
  const int dl = lane >> 3, slV = lane & 7;
  int koff[4], voff[4];
#pragma unroll
  for (int i = 0; i < 4; ++i) {
    int r = w * 16 + i * 4 + rl;
    int swr = (r ^ (r >> 3)) & 7;
    koff[i] = r * 256 + (((slK & 8) | ((slK & 7) ^ swr)) << 4);
    int d = w * 32 + i * 8 + dl;
    int swd = (d ^ (d >> 3)) & 7;
    voff[i] = d * 8192 + ((slV ^ swd) << 4);
  }
  const char* kpb = (const char*)Kp + (size_t)b * 1048576 + (size_t)s * NT * 16384;
  const char* vpb = (const char*)Vt + (size_t)b * 1048576 + (size_t)s * NT * 128;

  f32x16 oacc[4];
#pragma unroll
  for (int nf = 0; nf < 4; ++nf)
#pragma unroll
    for (int r = 0; r < 16; ++r) oacc[nf][r] = 0.0f;
  float m_run = -3.0e38f, lacc = 0.0f;

  auto stage = [&](int tt, int bufb) {
    const char* kb = kpb + (size_t)tt * 16384;
    const char* vb = vpb + (size_t)tt * 128;
    char* lk = smc + bufb + w * 4096;
    char* lv = smc + bufb + 16384 + w * 4096;
#pragma unroll
    for (int i = 0; i < 4; ++i) {
      gld_lds16(kb + koff[i], lk + i * 1024);
      gld_lds16(vb + voff[i], lv + i * 1024);
    }
  };

  stage(0, 0);
  stage(1, 32768);

  for (int t = 0; t < NT; ++t) {
    asm volatile("s_waitcnt vmcnt(8)" ::: "memory");
    __builtin_amdgcn_s_barrier();
    const char* kb = smc + (t & 1) * 32768;
    const char* vb = kb + 16384;

    f32x16 s0, s1;
#pragma unroll
    for (int i = 0; i < 16; ++i) { s0[i] = 0.0f; s1[i] = 0.0f; }
    __builtin_amdgcn_s_setprio(1);
#pragma unroll
    for (int db = 0; db < 8; ++db) {
      const int q = 2 * db + h;
      bf16x8 k0 = *(const bf16x8*)(kb + l31 * 256 + (((q & 8) | ((q & 7) ^ sw0)) << 4));
      bf16x8 k1 = *(const bf16x8*)(kb + (32 + l31) * 256 + (((q & 8) | ((q & 7) ^ sw1)) << 4));
      s0 = mfma32(k0, qf[db], s0);
      s1 = mfma32(k1, qf[db], s1);
    }
    __builtin_amdgcn_s_setprio(0);

    float tmax = fmaxf(s0[0], s1[0]);
#pragma unroll
    for (int i = 1; i < 16; ++i) tmax = fmaxf(tmax, fmaxf(s0[i], s1[i]));
    tmax = fmaxf(tmax, __shfl_xor(tmax, 32));
    if (__any(tmax > m_run + 62.0f)) {
      float mnew = fmaxf(m_run, tmax);
      float fac = exp2f((m_run - mnew) * CEXP);
      m_run = mnew;
      lacc *= fac;
#pragma unroll
      for (int r = 0; r < 16; ++r) {
        float fr = __shfl(fac, (r & 3) + 8 * (r >> 2) + 4 * h);
#pragma unroll
        for (int nf = 0; nf < 4; ++nf) oacc[nf][r] *= fr;
      }
    }
    const float mc = m_run * CEXP;
#pragma unroll
    for (int i = 0; i < 16; ++i) s0[i] = exp2f(fmaf(s0[i], CEXP, -mc));
#pragma unroll
    for (int i = 0; i < 16; ++i) s1[i] = exp2f(fmaf(s1[i], CEXP, -mc));
    float a0 = 0.f, a1 = 0.f, a2 = 0.f, a3 = 0.f;
#pragma unroll
    for (int i = 0; i < 16; i += 4) {
      a0 += s0[i] + s1[i];         a1 += s0[i + 1] + s1[i + 1];
      a2 += s0[i + 2] + s1[i + 2]; a3 += s0[i + 3] + s1[i + 3];
    }
    lacc += (a0 + a1) + (a2 + a3);

    __builtin_amdgcn_s_setprio(1);
    {
      bf16x8 pf = build_pf<0>(s0, h);
#pragma unroll
      for (int nf = 0; nf < 4; ++nf) {
        bf16x8 vf = *(const bf16x8*)(vb + (nf * 32 + l31) * 128 + (((0 + h) ^ swv[nf]) << 4));
        oacc[nf] = mfma32(pf, vf, oacc[nf]);
      }
    }
    {
      bf16x8 pf = build_pf<8>(s0, h);
#pragma unroll
      for (int nf = 0; nf < 4; ++nf) {
        bf16x8 vf = *(const bf16x8*)(vb + (nf * 32 + l31) * 128 + (((2 + h) ^ swv[nf]) << 4));
        oacc[nf] = mfma32(pf, vf, oacc[nf]);
      }
    }
    {
      bf16x8 pf = build_pf<0>(s1, h);
#pragma unroll
      for (int nf = 0; nf < 4; ++nf) {
        bf16x8 vf = *(const bf16x8*)(vb + (nf * 32 + l31) * 128 + (((4 + h) ^ swv[nf]) << 4));
        oacc[nf] = mfma32(pf, vf, oacc[nf]);
      }
    }
    {
      bf16x8 pf = build_pf<8>(s1, h);
#pragma unroll
      for (int nf = 0; nf < 4; ++nf) {
        bf16x8 vf = *(const bf16x8*)(vb + (nf * 32 + l31) * 128 + (((6 + h) ^ swv[nf]) << 4));
        oacc[nf] = mfma32(pf, vf, oacc[nf]);
      }
    }
    __builtin_amdgcn_s_setprio(0);

    __builtin_amdgcn_s_barrier();
    stage((t + 2) & (NT - 1), (t & 1) * 32768);
  }
  asm volatile("s_waitcnt vmcnt(0)" ::: "memory");

  lacc += __shfl_xor(lacc, 32);
  if (SPLIT == 1) {
    const float inv = 1.0f / lacc;
    float* ob = out + (size_t)(b * 4096 + qbase) * 128;
#pragma unroll
    for (int r = 0; r < 16; ++r) {
      const int rowD = (r & 3) + 8 * (r >> 2) + 4 * h;
      float ir = __shfl(inv, rowD);
#pragma unroll
      for (int nf = 0; nf < 4; ++nf)
        ob[(size_t)rowD * 128 + nf * 32 + l31] = oacc[nf][r] * ir;
    }
  } else {
    const int pb = s * 256 + b * 32 + qt;
    if (lane < 32) {
      Mpart[pb * 128 + w * 32 + l31] = m_run;
      Lpart[pb * 128 + w * 32 + l31] = lacc;
    }
    float* ob = Opart + ((size_t)pb * 128 + w * 32) * 128;
#pragma unroll
    for (int r = 0; r < 16; ++r) {
      const int rowD = (r & 3) + 8 * (r >> 2) + 4 * h;
#pragma unroll
      for (int nf = 0; nf < 4; ++nf)
        ob[(size_t)rowD * 128 + nf * 32 + l31] = oacc[nf][r];
    }
  }
}

// Combine 2 split partials. grid 4096 x 256: 8 rows/block, 32 lanes/row (float4).
__global__ __launch_bounds__(256) void combine_kernel(
    const float* __restrict__ Opart, const float* __restrict__ Mpart,
    const float* __restrict__ Lpart, float* __restrict__ out) {
  const int g = blockIdx.x * 8 + (threadIdx.x >> 5);
  const int lane32 = threadIdx.x & 31;
  const int b = g >> 12;
  const int pos = g & 4095;
  const int qt = pos >> 7;
  const int row = pos & 127;
  const int i0 = (b * 32 + qt) * 128 + row;
  const int i1 = (256 + b * 32 + qt) * 128 + row;
  const float m0 = Mpart[i0], m1 = Mpart[i1];
  const float l0 = Lpart[i0], l1 = Lpart[i1];
  const float m = fmaxf(m0, m1);
  const float w0 = exp2f((m0 - m) * CEXP_CONST);
  const float w1 = exp2f((m1 - m) * CEXP_CONST);
  const float inv = 1.0f / (w0 * l0 + w1 * l1);
  const float4 o0 = *(const float4*)(Opart + (size_t)i0 * 128 + lane32 * 4);
  const float4 o1 = *(const float4*)(Opart + (size_t)i1 * 128 + lane32 * 4);
  float4 o;
  o.x = (w0 * o0.x + w1 * o1.x) * inv;
  o.y = (w0 * o0.y + w1 * o1.y) * inv;
  o.z = (w0 * o0.z + w1 * o1.z) * inv;
  o.w = (w0 * o0.w + w1 * o1.w) * inv;
  *(float4*)(out + (size_t)g * 128 + lane32 * 4) = o;
}

extern "C" void kernel_launch(void* const* d_in, const int* in_sizes, int n_in,
                              void* d_out, int out_size, void* d_ws, size_t ws_size,
                              hipStream_t stream) {
  const float* q  = (const float*)d_in[0];
  const float* k  = (const float*)d_in[1];
  const float* v  = (const float*)d_in[2];
  const float* Wq = (const float*)d_in[3];
  const float* Wk = (const float*)d_in[4];
  const float* Wv = (const float*)d_in[5];
  float* out = (float*)d_out;
  char* ws = (char*)d_ws;
  bf16_t* Wt2 = (bf16_t*)(ws);
  bf16_t* Qp = (bf16_t*)(ws + (size_t)(1u << 20));
  bf16_t* Kp = (bf16_t*)(ws + (size_t)(9u << 20));
  bf16_t* Vt = (bf16_t*)(ws + (size_t)(17u << 20));
  float* Opart = (float*)(ws + (size_t)(32u << 20));
  float* Mpart = (float*)(ws + (size_t)(64u << 20));
  float* Lpart = (float*)(ws + (size_t)(64u << 20) + (256u << 10));

  hipLaunchKernelGGL(wt_kernel, dim3(1536), dim3(256), 0, stream, Wq, Wk, Wv, Wt2);
  hipLaunchKernelGGL(proj_kernel, dim3(1024, 3), dim3(256), 0, stream, q, k, v, Wt2, Qp, Kp, Vt);

  if (ws_size >= ((size_t)65 << 20)) {
    hipLaunchKernelGGL((attn_kernel<2>), dim3(512), dim3(256), 0, stream,
                       Qp, Kp, Vt, out, Opart, Mpart, Lpart);
    hipLaunchKernelGGL(combine_kernel, dim3(4096), dim3(256), 0, stream,
                       Opart, Mpart, Lpart, out);
  } else {
    hipLaunchKernelGGL((attn_kernel<1>), dim3(256), dim3(256), 0, stream,
                       Qp, Kp, Vt, out, Opart, Mpart, Lpart);
  }
}